// Round 1
// baseline (16122.911 us; speedup 1.0000x reference)
//
#include <hip/hip_runtime.h>
#include <hip/hip_bf16.h>
#include <hip/hip_cooperative_groups.h>

namespace cg = cooperative_groups;

#define B_ 8
#define T_ 256
#define N_ 32
#define D_ 128
#define S_ 8
#define V_ 32000
#define H_ 4
#define HD_ 32
#define NCHUNK 32
#define CH_ 8

__device__ __forceinline__ float gelu_f(float x){
    return 0.5f * x * (1.0f + erff(x * 0.70710678118654752440f));
}
__device__ __forceinline__ float sigm(float x){
    return 1.0f / (1.0f + expf(-x));
}

// -------------------- percepts = LN(gelu(raw @ ifc_w + b)) --------------------
__global__ void k_percepts(const int* __restrict__ idx, const float* __restrict__ emb,
                           const float* __restrict__ pos_emb, const float* __restrict__ ifc_w,
                           const float* __restrict__ ifc_b, const float* __restrict__ ifc_g,
                           const float* __restrict__ ifc_beta, float* __restrict__ percepts){
    int r = blockIdx.x;          // r = b*T + t
    int t = r % T_;
    int d = threadIdx.x;         // 128 threads
    __shared__ float raw[D_];
    __shared__ float red[D_];
    int tok = idx[r];
    raw[d] = emb[tok*D_ + d] + pos_emb[t*D_ + d];
    __syncthreads();
    float acc = ifc_b[d];
    #pragma unroll 8
    for (int k=0;k<D_;k++) acc += raw[k]*ifc_w[k*D_+d];
    float x = gelu_f(acc);
    red[d] = x; __syncthreads();
    for (int s=64;s>0;s>>=1){ if(d<s) red[d]+=red[d+s]; __syncthreads(); }
    float m = red[0]*(1.0f/D_); __syncthreads();
    float dv = x-m; red[d] = dv*dv; __syncthreads();
    for (int s=64;s>0;s>>=1){ if(d<s) red[d]+=red[d+s]; __syncthreads(); }
    float var = red[0]*(1.0f/D_);
    percepts[r*D_ + d] = dv * (1.0f/sqrtf(var + 1e-5f)) * ifc_g[d] + ifc_beta[d];
}

// ------ hoisted precompute: sensory, sgate-sensory-part, residual->out contribution ------
__global__ void __launch_bounds__(256) k_precomp(const float* __restrict__ percepts,
                          const float* __restrict__ sproj_w, const float* __restrict__ sproj_b,
                          const float* __restrict__ sgate_w,
                          const float* __restrict__ res_w, const float* __restrict__ res_b,
                          const float* __restrict__ out_w,
                          float* __restrict__ sensory, float* __restrict__ sg_sens,
                          float* __restrict__ outres){
    int blk = blockIdx.x;     // 256: b*32 + c
    int b = blk >> 5, c = blk & 31;
    int tid = threadIdx.x;    // 256
    __shared__ float p[CH_][D_];
    __shared__ float sens[CH_][S_*D_];
    __shared__ float resid[CH_][D_];
    int tbase = b*T_ + c*CH_;
    for (int i = tid; i < CH_*D_; i += 256) p[i>>7][i&127] = percepts[(tbase + (i>>7))*D_ + (i&127)];
    __syncthreads();
    for (int q=0;q<4;q++){
        int sd = tid + 256*q;
        float acc[CH_];
        #pragma unroll
        for(int i=0;i<CH_;i++) acc[i] = sproj_b[sd];
        for (int k=0;k<D_;k++){
            float w = sproj_w[k*(S_*D_) + sd];
            #pragma unroll
            for(int i=0;i<CH_;i++) acc[i] += p[i][k]*w;
        }
        #pragma unroll
        for(int i=0;i<CH_;i++){
            sens[i][sd] = acc[i];
            sensory[(size_t)(tbase+i)*(S_*D_) + sd] = acc[i];
        }
    }
    __syncthreads();
    {
        int d = tid & 127, h = tid >> 7;   // h: i-half
        float acc[4][S_];
        #pragma unroll
        for(int ii=0;ii<4;ii++)
            #pragma unroll
            for(int s=0;s<S_;s++) acc[ii][s]=0.f;
        for (int k=0;k<D_;k++){
            float w = sgate_w[(D_+k)*D_ + d];
            #pragma unroll
            for(int ii=0;ii<4;ii++){
                int i = h*4+ii;
                #pragma unroll
                for(int s=0;s<S_;s++) acc[ii][s] += sens[i][s*D_+k]*w;
            }
        }
        for(int ii=0;ii<4;ii++){ int i=h*4+ii;
            for(int s=0;s<S_;s++) sg_sens[((size_t)(tbase+i)*S_+s)*D_ + d] = acc[ii][s];
        }
    }
    __syncthreads();
    {
        int d = tid & 127, h = tid>>7;
        float acc[4];
        #pragma unroll
        for(int ii=0;ii<4;ii++) acc[ii]=res_b[d];
        for(int k=0;k<D_;k++){
            float w = res_w[k*D_+d];
            #pragma unroll
            for(int ii=0;ii<4;ii++) acc[ii] += p[h*4+ii][k]*w;
        }
        for(int ii=0;ii<4;ii++) resid[h*4+ii][d]=acc[ii];
    }
    __syncthreads();
    {
        int d = tid & 127, h = tid>>7;
        float acc[4];
        #pragma unroll
        for(int ii=0;ii<4;ii++) acc[ii]=0.f;
        for(int k=0;k<D_;k++){
            float w = out_w[(D_+k)*D_ + d];
            #pragma unroll
            for(int ii=0;ii<4;ii++) acc[ii] += resid[h*4+ii][k]*w;
        }
        for(int ii=0;ii<4;ii++) outres[(size_t)(tbase+h*4+ii)*D_ + d] = acc[ii];
    }
}

// ==================== persistent cooperative chunk-loop kernel ====================
struct LoopArgs {
    const float* sensory; const float* sg_sens;
    const float* sgate_w; const float* sgate_b;
    const float* sal_w;   const float* sal_b;
    const float* out_w;   const float* out_b;  const float* outres;
    const float* bcast_w; const float* bcast_b; const float* wln_g; const float* wln_b;
    const float* cq_w; const float* cq_b; const float* ck_w; const float* ck_b;
    const float* cv_w; const float* cv_b; const float* co_w; const float* co_b;
    const float* cln_g; const float* cln_b;
    const float* P_w;  const float* P_b;  const float* D1_w; const float* D1_b;
    const float* D2_w; const float* D2_b; const float* G_w;  const float* G_b;
    const float* SM_w; const float* SM_b; const float* PR_w; const float* PR_b;
    const float* ln_g; const float* ln_b;
    float* states; float* states2; float* bcastv; float* meanv;
    float* prediction; float* projb;
};

// LDS layout (floats). Phase1: ST states (4096) | KT 32x129 | VT 32x129 | SA | SB.
// Scan aliases ns/salv/wtsv/wsv into the KT region; red->SA, proj partials->SB.
// Phase2 (brains) reuses smem[0..7168) as 4 units x 1792.
#define ST_O 0
#define KT_O 4096
#define VT_O 8224
#define SA_O 12352
#define SB_O 13376
#define SMEM_N 14400   // 57.6 KB

__global__ void __launch_bounds__(1024) k_loop(LoopArgs a){
    cg::grid_group grid = cg::this_grid();
    const int bid = blockIdx.x;     // 64 blocks
    const int tid = threadIdx.x;    // 1024 threads
    __shared__ float smem[SMEM_N];

    for (int c=0; c<NCHUNK; c++){
        // ---------------- phase 1: scan + QKV + attention (blocks 0..7) ----------------
        if (bid < B_){
            const int b = bid;
            float* st   = &smem[ST_O];
            float* ns   = &smem[KT_O];
            float* salv = &smem[KT_O+1024];
            float* wtsv = &smem[KT_O+1056];
            float* wsv  = &smem[KT_O+1088];
            float* redb = &smem[SA_O];
            float* ppart= &smem[SB_O];
            for (int i=tid;i<N_*D_;i+=1024) st[i] = a.states[b*N_*D_+i];
            __syncthreads();
            const int s = tid >> 7, d = tid & 127;
            for (int step=0; step<CH_; step++){
                const int tg = b*T_ + c*CH_ + step;
                // sgate state-part + precomputed sensory part
                float acc = a.sg_sens[((size_t)tg*S_+s)*D_+d] + a.sgate_b[d];
                const float* stp = &st[s*D_];
                #pragma unroll 8
                for (int k=0;k<D_;k++) acc += stp[k]*a.sgate_w[k*D_+d];
                float sg = sigm(acc);
                float sv = a.sensory[((size_t)tg*S_+s)*D_+d];
                ns[tid] = sg*stp[d] + (1.0f-sg)*sv;
                __syncthreads();
                st[tid] = ns[tid];
                __syncthreads();
                // sal over all 32 nodes
                if (tid < 512){
                    int nn = tid >> 4, l = tid & 15;
                    float pa = 0.f;
                    #pragma unroll
                    for (int j=0;j<8;j++) pa += st[nn*D_ + l + 16*j]*a.sal_w[l+16*j];
                    #pragma unroll
                    for (int off=8;off;off>>=1) pa += __shfl_down(pa, off, 16);
                    if (l==0) salv[nn] = pa + a.sal_b[0];
                }
                __syncthreads();
                if (tid < 64){
                    float v = (tid<N_)? salv[tid]*5.0f : -1e30f;
                    float m = v;
                    #pragma unroll
                    for (int off=32;off;off>>=1) m = fmaxf(m, __shfl_xor(m, off, 64));
                    float e = (tid<N_)? expf(v-m) : 0.f;
                    float Z = e;
                    #pragma unroll
                    for (int off=32;off;off>>=1) Z += __shfl_xor(Z, off, 64);
                    if (tid<N_) wtsv[tid] = e/Z;
                }
                __syncthreads();
                if (tid < D_){
                    float w = 0.f;
                    #pragma unroll 4
                    for (int n=0;n<N_;n++) w += wtsv[n]*st[n*D_+tid];
                    wsv[tid] = w;
                }
                __syncthreads();
                // out-projection with 8-way k-split (latency /8)
                {
                    const int ks = tid >> 7;
                    float ap = 0.f;
                    #pragma unroll
                    for (int k2=0;k2<16;k2++){ int k = ks*16+k2; ap += wsv[k]*a.out_w[k*D_+d]; }
                    ppart[tid] = ap;
                }
                __syncthreads();
                if (tid < D_){
                    float a2 = a.out_b[tid] + a.outres[(size_t)tg*D_+tid];
                    #pragma unroll
                    for (int j=0;j<8;j++) a2 += ppart[j*128+tid];
                    a.projb[(size_t)tg*D_+tid] = gelu_f(a2);
                }
                if (step==CH_-1){
                    float a3 = 0.f;
                    if (tid<D_){
                        a3 = a.bcast_b[tid];
                        #pragma unroll 8
                        for (int k=0;k<D_;k++) a3 += wsv[k]*a.bcast_w[k*D_+tid];
                        redb[tid] = a3;
                    }
                    __syncthreads();
                    for (int sh=64;sh;sh>>=1){ if(tid<sh) redb[tid]+=redb[tid+sh]; __syncthreads(); }
                    float mb = redb[0]*(1.0f/D_);
                    __syncthreads();
                    float dvv = a3-mb;
                    if (tid<D_) redb[tid] = dvv*dvv;
                    __syncthreads();
                    for (int sh=64;sh;sh>>=1){ if(tid<sh) redb[tid]+=redb[tid+sh]; __syncthreads(); }
                    float vb = redb[0]*(1.0f/D_);
                    if (tid<D_) a.bcastv[b*D_+tid] = dvv*(1.0f/sqrtf(vb+1e-5f))*a.wln_g[tid]+a.wln_b[tid];
                }
                __syncthreads();
            }
            // ---- QKV + attention + co + cln-LN, all in LDS ----
            {
                const int g = tid >> 7, d2 = tid & 127;
                // K,V for all 32 nodes; one weight fetch feeds 4 nodes
                float aK[4], aV[4];
                #pragma unroll
                for (int q=0;q<4;q++){ aK[q]=a.ck_b[d2]; aV[q]=a.cv_b[d2]; }
                #pragma unroll 4
                for (int k=0;k<D_;k++){
                    float wk = a.ck_w[k*D_+d2];
                    float wv = a.cv_w[k*D_+d2];
                    #pragma unroll
                    for (int q=0;q<4;q++){
                        float x = st[(q*8+g)*D_+k];
                        aK[q] += x*wk; aV[q] += x*wv;
                    }
                }
                #pragma unroll
                for (int q=0;q<4;q++){
                    smem[KT_O+(q*8+g)*129+d2] = aK[q];
                    smem[VT_O+(q*8+g)*129+d2] = aV[q];
                }
                __syncthreads();
                for (int ni=0;ni<4;ni++){
                    const int n = ni*8+g;
                    // Q for this node -> SA
                    float aq = a.cq_b[d2];
                    #pragma unroll 4
                    for (int k=0;k<D_;k++) aq += st[n*D_+k]*a.cq_w[k*D_+d2];
                    smem[SA_O+g*128+d2] = aq;
                    __syncthreads();
                    // scores + softmax (per head, 32 keys) -> SB
                    {
                        const int h = d2>>5, m = d2&31;
                        float sdot = 0.f;
                        #pragma unroll
                        for (int j=0;j<HD_;j++) sdot += smem[SA_O+g*128+h*32+j]*smem[KT_O+m*129+h*32+j];
                        sdot *= 0.17677669529663687f; // 1/sqrt(32)
                        float mx = sdot;
                        #pragma unroll
                        for (int off=16;off;off>>=1) mx = fmaxf(mx, __shfl_xor(mx, off, 32));
                        float e = expf(sdot-mx);
                        float Z = e;
                        #pragma unroll
                        for (int off=16;off;off>>=1) Z += __shfl_xor(Z, off, 32);
                        smem[SB_O+g*128+h*32+m] = e/Z;
                    }
                    __syncthreads();
                    // msg = attn @ V -> SA (Q is dead)
                    {
                        const int h = d2>>5;
                        float mm = 0.f;
                        #pragma unroll 8
                        for (int m2=0;m2<N_;m2++) mm += smem[SB_O+g*128+h*32+m2]*smem[VT_O+m2*129+d2];
                        smem[SA_O+g*128+d2] = mm;
                    }
                    __syncthreads();
                    // co + residual + LN (one-pass sum/sumsq via shfl)
                    float acc2 = a.co_b[d2];
                    #pragma unroll 4
                    for (int k=0;k<D_;k++) acc2 += smem[SA_O+g*128+k]*a.co_w[k*D_+d2];
                    float x = st[n*D_+d2] + acc2;
                    float s1 = x, s2 = x*x;
                    #pragma unroll
                    for (int off=32;off;off>>=1){
                        s1 += __shfl_xor(s1, off, 64);
                        s2 += __shfl_xor(s2, off, 64);
                    }
                    if ((tid&63)==0){
                        smem[SB_O + g*4 + (d2>>6)*2    ] = s1;
                        smem[SB_O + g*4 + (d2>>6)*2 + 1] = s2;
                    }
                    __syncthreads();
                    s1 = smem[SB_O+g*4]   + smem[SB_O+g*4+2];
                    s2 = smem[SB_O+g*4+1] + smem[SB_O+g*4+3];
                    float mn  = s1*(1.0f/D_);
                    float var = s2*(1.0f/D_) - mn*mn;
                    float st2v = (x-mn)*(1.0f/sqrtf(var+1e-5f))*a.cln_g[d2]+a.cln_b[d2];
                    a.states2[((size_t)b*N_+n)*D_+d2] = st2v;
                    st[n*D_+d2] = st2v;   // row n not read again this chunk except mean
                    __syncthreads();
                }
                // node-mean of states2 for brains' "incoming"
                if (tid < D_){
                    float sm_ = 0.f;
                    #pragma unroll 4
                    for (int n2=0;n2<N_;n2++) sm_ += st[n2*D_+tid];
                    a.meanv[b*D_+tid] = sm_*(1.0f/N_);
                }
            }
        }
        __threadfence();
        grid.sync();
        // ---------------- phase 2: brains (all 64 blocks, 4 units each) ----------------
        {
            const int x8 = bid & 7, b2 = bid >> 3;   // node group -> XCD, batch
            const int u = tid >> 8;                   // unit 0..3
            const int utid = tid & 255, d = utid & 127, h = utid >> 7;
            const int n = x8 + 8*u;
            float* UB    = &smem[u*1792];
            float* pin   = UB;          // 384
            float* strow = UB+384;      // 128
            float* part  = UB+512;      // 256
            float* din   = UB+768;      // 256
            float* gin   = UB+1024;     // 256
            float* dec   = UB+1280;     // 128
            float* nsv   = UB+1408;     // 128
            float* red   = UB+1536;     // 256
            const size_t rowb = ((size_t)b2*N_+n)*D_;
            float inc = a.meanv[b2*D_+d];
            if (h==0) strow[d] = a.states2[rowb+d];
            float pr = a.prediction[rowb+d];
            float diff = inc - pr;
            red[utid] = (h==0)? diff*diff : 0.f;
            __syncthreads();
            for (int sh=128;sh;sh>>=1){ if (utid<sh) red[utid]+=red[utid+sh]; __syncthreads(); }
            float pe = red[0]*(1.0f/D_);
            float surprise = (c>0)? sigm(pe*10.0f) : 0.0f;
            float scale = 1.0f + 0.5f*surprise;
            __syncthreads();
            if (h==0){
                pin[d]      = inc*scale;
                pin[D_+d]   = a.bcastv[b2*D_+d];
                pin[2*D_+d] = strow[d];
            }
            __syncthreads();
            // P: K=384 -> perception (gelu) into din[0:128]
            {
                const float* Wn = a.P_w + ((size_t)n*384 + h*192)*D_ + d;
                float ac=0;
                #pragma unroll 4
                for (int k=0;k<192;k++) ac += pin[h*192+k]*Wn[(size_t)k*D_];
                __syncthreads();
                part[h*128+d]=ac;
                __syncthreads();
                if (h==0) din[d] = gelu_f(part[d]+part[128+d]+a.P_b[n*D_+d]);
                __syncthreads();
            }
            // SM: K=128 -> self_pred into din[128:256]
            {
                const float* Wn = a.SM_w + ((size_t)n*128 + h*64)*D_ + d;
                float ac=0;
                #pragma unroll 4
                for (int k=0;k<64;k++) ac += strow[h*64+k]*Wn[(size_t)k*D_];
                __syncthreads();
                part[h*128+d]=ac;
                __syncthreads();
                if (h==0) din[D_+d] = part[d]+part[128+d]+a.SM_b[n*D_+d];
                __syncthreads();
            }
            // D1: K=256 -> h1 (gelu) into pin[0:128]
            {
                const float* Wn = a.D1_w + ((size_t)n*256 + h*128)*D_ + d;
                float ac=0;
                #pragma unroll 4
                for (int k=0;k<128;k++) ac += din[h*128+k]*Wn[(size_t)k*D_];
                __syncthreads();
                part[h*128+d]=ac;
                __syncthreads();
                if (h==0) pin[d] = gelu_f(part[d]+part[128+d]+a.D1_b[n*D_+d]);
                __syncthreads();
            }
            // D2: K=128 -> decision
            {
                const float* Wn = a.D2_w + ((size_t)n*128 + h*64)*D_ + d;
                float ac=0;
                #pragma unroll 4
                for (int k=0;k<64;k++) ac += pin[h*64+k]*Wn[(size_t)k*D_];
                __syncthreads();
                part[h*128+d]=ac;
                __syncthreads();
                if (h==0){ float v = part[d]+part[128+d]+a.D2_b[n*D_+d]; dec[d]=v; gin[d]=strow[d]; gin[D_+d]=v; }
                __syncthreads();
            }
            // G: K=256 -> gate
            {
                const float* Wn = a.G_w + ((size_t)n*256 + h*128)*D_ + d;
                float ac=0;
                #pragma unroll 4
                for (int k=0;k<128;k++) ac += gin[h*128+k]*Wn[(size_t)k*D_];
                __syncthreads();
                part[h*128+d]=ac;
                __syncthreads();
            }
            float gg=0.f, pre=0.f;
            if (h==0){
                gg = sigm(part[d]+part[128+d]+a.G_b[n*D_+d]);
                pre = gg*dec[d] + (1.0f-gg)*strow[d];
            }
            red[utid] = (h==0)? pre : 0.f;
            __syncthreads();
            for (int sh=128;sh;sh>>=1){ if (utid<sh) red[utid]+=red[utid+sh]; __syncthreads(); }
            float mn = red[0]*(1.0f/D_);
            __syncthreads();
            float dv2 = pre-mn;
            red[utid] = (h==0)? dv2*dv2 : 0.f;
            __syncthreads();
            for (int sh=128;sh;sh>>=1){ if (utid<sh) red[utid]+=red[utid+sh]; __syncthreads(); }
            float var = red[0]*(1.0f/D_);
            __syncthreads();
            if (h==0){
                float nv = dv2*(1.0f/sqrtf(var+1e-5f))*a.ln_g[d]+a.ln_b[d];
                nsv[d]=nv;
                a.states[rowb+d]=nv;
            }
            __syncthreads();
            // PR: K=128 -> prediction
            {
                const float* Wn = a.PR_w + ((size_t)n*128 + h*64)*D_ + d;
                float ac=0;
                #pragma unroll 4
                for (int k=0;k<64;k++) ac += nsv[h*64+k]*Wn[(size_t)k*D_];
                __syncthreads();
                part[h*128+d]=ac;
                __syncthreads();
                if (h==0) a.prediction[rowb+d] = part[d]+part[128+d]+a.PR_b[n*D_+d];
            }
        }
        __threadfence();
        grid.sync();
    }
}

// -------------------- f32 -> bf16 --------------------
__global__ void k_tobf16(const float* __restrict__ src, __hip_bfloat16* __restrict__ dst, int nelem){
    int i = blockIdx.x*256 + threadIdx.x;
    int stride = gridDim.x*256;
    for (; i<nelem; i+=stride) dst[i] = __float2bfloat16(src[i]);
}

// -------------------- final logits GEMM: (2048x128) @ (128x32000) + bias --------------------
typedef __attribute__((ext_vector_type(8))) short short8;
typedef __attribute__((ext_vector_type(4))) float f32x4;

__global__ void __launch_bounds__(256) k_gemm(const __hip_bfloat16* __restrict__ A,  // proj bf16, M x 128
                       const __hip_bfloat16* __restrict__ Bv,                        // emb bf16, V x 128
                       const float* __restrict__ out_bias,
                       float* __restrict__ out){
    int vblk = blockIdx.x;   // 125 blocks * 256 v
    int mblk = blockIdx.y;   // 32 blocks * 64 m
    int tid = threadIdx.x;
    int wave = tid >> 6, lane = tid & 63;
    int l16 = lane & 15, quad = lane >> 4;
    int mrow = mblk*64 + wave*16 + l16;
    f32x4 acc[16];
    #pragma unroll
    for (int j=0;j<16;j++){ f32x4 z = {0.f,0.f,0.f,0.f}; acc[j]=z; }
    short8 afr[4];
    const short* Ap = reinterpret_cast<const short*>(A);
    #pragma unroll
    for (int ks=0;ks<4;ks++)
        afr[ks] = *reinterpret_cast<const short8*>(Ap + mrow*128 + ks*32 + quad*8);
    const short* Bp = reinterpret_cast<const short*>(Bv);
    int vcolbase = vblk*256;
    #pragma unroll
    for (int jj=0;jj<16;jj++){
        int v = vcolbase + jj*16 + l16;
        #pragma unroll
        for (int ks=0;ks<4;ks++){
            short8 bfr = *reinterpret_cast<const short8*>(Bp + (size_t)v*128 + ks*32 + quad*8);
            acc[jj] = __builtin_amdgcn_mfma_f32_16x16x32_bf16(afr[ks], bfr, acc[jj], 0,0,0);
        }
    }
    int mbase = mblk*64 + wave*16 + quad*4;
    #pragma unroll
    for (int jj=0;jj<16;jj++){
        int v = vcolbase + jj*16 + l16;
        float bias = out_bias[v];
        #pragma unroll
        for (int r=0;r<4;r++){
            out[(size_t)(mbase+r)*V_ + v] = acc[jj][r] + bias;
        }
    }
}

extern "C" void kernel_launch(void* const* d_in, const int* in_sizes, int n_in,
                              void* d_out, int out_size, void* d_ws, size_t ws_size,
                              hipStream_t stream){
    (void)in_sizes; (void)n_in; (void)out_size; (void)ws_size;
    const int*   idx      = (const int*)  d_in[0];
    const float* emb      = (const float*)d_in[1];
    const float* pos_emb  = (const float*)d_in[2];
    const float* ifc_w    = (const float*)d_in[3];
    const float* ifc_b    = (const float*)d_in[4];
    const float* ifc_g    = (const float*)d_in[5];
    const float* ifc_beta = (const float*)d_in[6];
    const float* sproj_w  = (const float*)d_in[7];
    const float* sproj_b  = (const float*)d_in[8];
    const float* sgate_w  = (const float*)d_in[9];
    const float* sgate_b  = (const float*)d_in[10];
    const float* P_w  = (const float*)d_in[11];
    const float* P_b  = (const float*)d_in[12];
    const float* D1_w = (const float*)d_in[13];
    const float* D1_b = (const float*)d_in[14];
    const float* D2_w = (const float*)d_in[15];
    const float* D2_b = (const float*)d_in[16];
    // d_in[17], d_in[18]: A_w, A_b -- unused by the reference output
    const float* G_w  = (const float*)d_in[19];
    const float* G_b  = (const float*)d_in[20];
    const float* SM_w = (const float*)d_in[21];
    const float* SM_b = (const float*)d_in[22];
    const float* PR_w = (const float*)d_in[23];
    const float* PR_b = (const float*)d_in[24];
    const float* cq_w = (const float*)d_in[25];
    const float* cq_b = (const float*)d_in[26];
    const float* ck_w = (const float*)d_in[27];
    const float* ck_b = (const float*)d_in[28];
    const float* cv_w = (const float*)d_in[29];
    const float* cv_b = (const float*)d_in[30];
    const float* co_w = (const float*)d_in[31];
    const float* co_b = (const float*)d_in[32];
    const float* cln_g = (const float*)d_in[33];
    const float* cln_b = (const float*)d_in[34];
    const float* sal_w = (const float*)d_in[35];
    const float* sal_b = (const float*)d_in[36];
    const float* bcast_w = (const float*)d_in[37];
    const float* bcast_b = (const float*)d_in[38];
    const float* wln_g = (const float*)d_in[39];
    const float* wln_b = (const float*)d_in[40];
    const float* res_w = (const float*)d_in[41];
    const float* res_b = (const float*)d_in[42];
    const float* out_w = (const float*)d_in[43];
    const float* out_b = (const float*)d_in[44];
    const float* out_bias = (const float*)d_in[45];
    const float* ln_g = (const float*)d_in[46];
    const float* ln_b = (const float*)d_in[47];

    float* ws = (float*)d_ws;
    float* states     = ws + 0;          // 32768
    float* prediction = ws + 32768;      // 32768
    float* states2    = ws + 65536;      // 32768
    float* bcastv     = ws + 98304;      // 1024
    float* meanv      = ws + 99328;      // 1024 (reuses old Qb slot)
    float* percepts   = ws + 197632;     // 262144
    float* sensory    = ws + 459776;     // 2097152
    float* sg_sens    = ws + 2556928;    // 2097152
    float* outresb    = ws + 4654080;    // 262144
    float* projb      = ws + 4916224;    // 262144
    __hip_bfloat16* proj_bf = (__hip_bfloat16*)(ws + 5178368);  // 262144 bf16
    __hip_bfloat16* emb_bf  = (__hip_bfloat16*)(ws + 5309440);  // 4096000 bf16

    // zero the carried state (states + prediction are contiguous)
    hipMemsetAsync(states, 0, 2*32768*sizeof(float), stream);

    k_tobf16<<<512,256,0,stream>>>(emb, emb_bf, V_*D_);
    k_percepts<<<B_*T_,128,0,stream>>>(idx, emb, pos_emb, ifc_w, ifc_b, ifc_g, ifc_beta, percepts);
    k_precomp<<<256,256,0,stream>>>(percepts, sproj_w, sproj_b, sgate_w, res_w, res_b, out_w,
                                    sensory, sg_sens, outresb);

    LoopArgs la;
    la.sensory = sensory; la.sg_sens = sg_sens;
    la.sgate_w = sgate_w; la.sgate_b = sgate_b;
    la.sal_w = sal_w; la.sal_b = sal_b;
    la.out_w = out_w; la.out_b = out_b; la.outres = outresb;
    la.bcast_w = bcast_w; la.bcast_b = bcast_b; la.wln_g = wln_g; la.wln_b = wln_b;
    la.cq_w = cq_w; la.cq_b = cq_b; la.ck_w = ck_w; la.ck_b = ck_b;
    la.cv_w = cv_w; la.cv_b = cv_b; la.co_w = co_w; la.co_b = co_b;
    la.cln_g = cln_g; la.cln_b = cln_b;
    la.P_w = P_w; la.P_b = P_b; la.D1_w = D1_w; la.D1_b = D1_b;
    la.D2_w = D2_w; la.D2_b = D2_b; la.G_w = G_w; la.G_b = G_b;
    la.SM_w = SM_w; la.SM_b = SM_b; la.PR_w = PR_w; la.PR_b = PR_b;
    la.ln_g = ln_g; la.ln_b = ln_b;
    la.states = states; la.states2 = states2; la.bcastv = bcastv; la.meanv = meanv;
    la.prediction = prediction; la.projb = projb;
    void* kargs[] = { &la };
    hipLaunchCooperativeKernel((const void*)k_loop, dim3(64), dim3(1024), kargs, 0, stream);

    k_tobf16<<<256,256,0,stream>>>(projb, proj_bf, B_*T_*D_);
    k_gemm<<<dim3(125,32),256,0,stream>>>(proj_bf, emb_bf, out_bias, (float*)d_out);
}

// Round 3
// 4298.987 us; speedup vs baseline: 3.7504x; 3.7504x over previous
//
#include <hip/hip_runtime.h>
#include <hip/hip_bf16.h>

#define B_ 8
#define T_ 256
#define N_ 32
#define D_ 128
#define S_ 8
#define V_ 32000
#define H_ 4
#define HD_ 32
#define NCHUNK 32
#define CH_ 8

__device__ __forceinline__ float gelu_f(float x){
    return 0.5f * x * (1.0f + erff(x * 0.70710678118654752440f));
}
__device__ __forceinline__ float sigm(float x){
    return 1.0f / (1.0f + expf(-x));
}

typedef __attribute__((ext_vector_type(4))) float f32x4v;

// -------------------- percepts = LN(gelu(raw @ ifc_w + b)) --------------------
__global__ void k_percepts(const int* __restrict__ idx, const float* __restrict__ emb,
                           const float* __restrict__ pos_emb, const float* __restrict__ ifc_w,
                           const float* __restrict__ ifc_b, const float* __restrict__ ifc_g,
                           const float* __restrict__ ifc_beta, float* __restrict__ percepts){
    int r = blockIdx.x;          // r = b*T + t
    int t = r % T_;
    int d = threadIdx.x;         // 128 threads
    __shared__ float raw[D_];
    __shared__ float red[D_];
    int tok = idx[r];
    raw[d] = emb[tok*D_ + d] + pos_emb[t*D_ + d];
    __syncthreads();
    float acc = ifc_b[d];
    #pragma unroll 8
    for (int k=0;k<D_;k++) acc += raw[k]*ifc_w[k*D_+d];
    float x = gelu_f(acc);
    red[d] = x; __syncthreads();
    for (int s=64;s>0;s>>=1){ if(d<s) red[d]+=red[d+s]; __syncthreads(); }
    float m = red[0]*(1.0f/D_); __syncthreads();
    float dv = x-m; red[d] = dv*dv; __syncthreads();
    for (int s=64;s>0;s>>=1){ if(d<s) red[d]+=red[d+s]; __syncthreads(); }
    float var = red[0]*(1.0f/D_);
    percepts[r*D_ + d] = dv * (1.0f/sqrtf(var + 1e-5f)) * ifc_g[d] + ifc_beta[d];
}

// ------ hoisted precompute: sensory, sgate-sensory-part, residual->out contribution ------
__global__ void __launch_bounds__(256) k_precomp(const float* __restrict__ percepts,
                          const float* __restrict__ sproj_w, const float* __restrict__ sproj_b,
                          const float* __restrict__ sgate_w,
                          const float* __restrict__ res_w, const float* __restrict__ res_b,
                          const float* __restrict__ out_w,
                          float* __restrict__ sensory, float* __restrict__ sg_sens,
                          float* __restrict__ outres){
    int blk = blockIdx.x;     // 256: b*32 + c
    int b = blk >> 5, c = blk & 31;
    int tid = threadIdx.x;    // 256
    __shared__ float p[CH_][D_];
    __shared__ float sens[CH_][S_*D_];
    __shared__ float resid[CH_][D_];
    int tbase = b*T_ + c*CH_;
    for (int i = tid; i < CH_*D_; i += 256) p[i>>7][i&127] = percepts[(tbase + (i>>7))*D_ + (i&127)];
    __syncthreads();
    for (int q=0;q<4;q++){
        int sd = tid + 256*q;
        float acc[CH_];
        #pragma unroll
        for(int i=0;i<CH_;i++) acc[i] = sproj_b[sd];
        for (int k=0;k<D_;k++){
            float w = sproj_w[k*(S_*D_) + sd];
            #pragma unroll
            for(int i=0;i<CH_;i++) acc[i] += p[i][k]*w;
        }
        #pragma unroll
        for(int i=0;i<CH_;i++){
            sens[i][sd] = acc[i];
            sensory[(size_t)(tbase+i)*(S_*D_) + sd] = acc[i];
        }
    }
    __syncthreads();
    {
        int d = tid & 127, h = tid >> 7;   // h: i-half
        float acc[4][S_];
        #pragma unroll
        for(int ii=0;ii<4;ii++)
            #pragma unroll
            for(int s=0;s<S_;s++) acc[ii][s]=0.f;
        for (int k=0;k<D_;k++){
            float w = sgate_w[(D_+k)*D_ + d];
            #pragma unroll
            for(int ii=0;ii<4;ii++){
                int i = h*4+ii;
                #pragma unroll
                for(int s=0;s<S_;s++) acc[ii][s] += sens[i][s*D_+k]*w;
            }
        }
        for(int ii=0;ii<4;ii++){ int i=h*4+ii;
            for(int s=0;s<S_;s++) sg_sens[((size_t)(tbase+i)*S_+s)*D_ + d] = acc[ii][s];
        }
    }
    __syncthreads();
    {
        int d = tid & 127, h = tid>>7;
        float acc[4];
        #pragma unroll
        for(int ii=0;ii<4;ii++) acc[ii]=res_b[d];
        for(int k=0;k<D_;k++){
            float w = res_w[k*D_+d];
            #pragma unroll
            for(int ii=0;ii<4;ii++) acc[ii] += p[h*4+ii][k]*w;
        }
        for(int ii=0;ii<4;ii++) resid[h*4+ii][d]=acc[ii];
    }
    __syncthreads();
    {
        int d = tid & 127, h = tid>>7;
        float acc[4];
        #pragma unroll
        for(int ii=0;ii<4;ii++) acc[ii]=0.f;
        for(int k=0;k<D_;k++){
            float w = out_w[(D_+k)*D_ + d];
            #pragma unroll
            for(int ii=0;ii<4;ii++) acc[ii] += resid[h*4+ii][k]*w;
        }
        for(int ii=0;ii<4;ii++) outres[(size_t)(tbase+h*4+ii)*D_ + d] = acc[ii];
    }
}

// ============ fused per-chunk kernel: scan (8 steps) + QKV + attention + cln-LN ============
// one block per batch b, 1024 threads.
// LDS layout (floats):
#define ST_O   0        // 4096  : states 32x128
#define SGW_O  4096     // 16384 : staged sgate_w[128][128]
#define KT_O   20480    // 4128  : K rows 32x129     (scan: ns[1024])
#define VT_O   24608    // 4128  : V rows 32x129     (scan: ppart[1024])
#define QT_O   28736    // 4128  : Q rows -> MSG rows (scan: wsv/salv/wtsv/redb)
#define AW_O   32864    // 1024  : attn weights, 8 groups x (4 heads x 32)
#define RED_O  33888    // 64    : LN partial sums
#define SMEM_A 33952    // 135.8 KB (gfx950 allows up to 160 KB/workgroup)

__global__ void __launch_bounds__(1024) k_fused(int c,
        const float* __restrict__ sensory, const float* __restrict__ sg_sens,
        const float* __restrict__ sgate_w, const float* __restrict__ sgate_b,
        const float* __restrict__ sal_w, const float* __restrict__ sal_b,
        const float* __restrict__ out_w, const float* __restrict__ out_b,
        const float* __restrict__ outres,
        const float* __restrict__ bcast_w, const float* __restrict__ bcast_b,
        const float* __restrict__ wln_g, const float* __restrict__ wln_b,
        const float* __restrict__ cq_w, const float* __restrict__ cq_b,
        const float* __restrict__ ck_w, const float* __restrict__ ck_b,
        const float* __restrict__ cv_w, const float* __restrict__ cv_b,
        const float* __restrict__ co_w, const float* __restrict__ co_b,
        const float* __restrict__ cln_g, const float* __restrict__ cln_b,
        const float* __restrict__ states, float* __restrict__ states2,
        float* __restrict__ bcastv, float* __restrict__ meanv,
        float* __restrict__ projb){
    const int b = blockIdx.x;
    const int tid = threadIdx.x;
    __shared__ float smem[SMEM_A];
    float* st  = &smem[ST_O];
    float* sgw = &smem[SGW_O];

    for (int i=tid;i<N_*D_;i+=1024) st[i] = states[b*N_*D_+i];
    // stage sgate_w into LDS (same [k][d] layout as global)
    {
        const f32x4v* gw = reinterpret_cast<const f32x4v*>(sgate_w);
        f32x4v* lw = reinterpret_cast<f32x4v*>(sgw);
        for (int i=tid;i<D_*D_/4;i+=1024) lw[i] = gw[i];
    }
    __syncthreads();

    // ---------------- scan: 8 timesteps ----------------
    {
        float* ns    = &smem[KT_O];          // 1024
        float* ppart = &smem[VT_O];          // 1024
        float* wsv   = &smem[QT_O];          // 128
        float* salv  = &smem[QT_O+128];      // 32
        float* wtsv  = &smem[QT_O+160];      // 32
        float* redb  = &smem[QT_O+192];      // 128
        const int s = tid >> 7, d = tid & 127;
        for (int step=0; step<CH_; step++){
            const int tg = b*T_ + c*CH_ + step;
            float acc = sg_sens[((size_t)tg*S_+s)*D_+d] + sgate_b[d];
            const float* stp = &st[s*D_];
            #pragma unroll 8
            for (int k=0;k<D_;k++) acc += stp[k]*sgw[k*D_+d];
            float sg = sigm(acc);
            float sv = sensory[((size_t)tg*S_+s)*D_+d];
            ns[tid] = sg*stp[d] + (1.0f-sg)*sv;
            __syncthreads();
            st[tid] = ns[tid];
            __syncthreads();
            // sal over all 32 nodes
            if (tid < 512){
                int nn = tid >> 4, l = tid & 15;
                float pa = 0.f;
                #pragma unroll
                for (int j=0;j<8;j++) pa += st[nn*D_ + l + 16*j]*sal_w[l+16*j];
                #pragma unroll
                for (int off=8;off;off>>=1) pa += __shfl_down(pa, off, 16);
                if (l==0) salv[nn] = pa + sal_b[0];
            }
            __syncthreads();
            if (tid < 64){
                float v = (tid<N_)? salv[tid]*5.0f : -1e30f;
                float m = v;
                #pragma unroll
                for (int off=32;off;off>>=1) m = fmaxf(m, __shfl_xor(m, off, 64));
                float e = (tid<N_)? expf(v-m) : 0.f;
                float Z = e;
                #pragma unroll
                for (int off=32;off;off>>=1) Z += __shfl_xor(Z, off, 64);
                if (tid<N_) wtsv[tid] = e/Z;
            }
            __syncthreads();
            if (tid < D_){
                float w = 0.f;
                #pragma unroll 4
                for (int n=0;n<N_;n++) w += wtsv[n]*st[n*D_+tid];
                wsv[tid] = w;
            }
            __syncthreads();
            // out-projection with 8-way k-split
            {
                const int ks = tid >> 7;
                float ap = 0.f;
                #pragma unroll
                for (int k2=0;k2<16;k2++){ int k = ks*16+k2; ap += wsv[k]*out_w[k*D_+d]; }
                ppart[tid] = ap;
            }
            __syncthreads();
            if (tid < D_){
                float a2 = out_b[tid] + outres[(size_t)tg*D_+tid];
                #pragma unroll
                for (int j=0;j<8;j++) a2 += ppart[j*128+tid];
                projb[(size_t)tg*D_+tid] = gelu_f(a2);
            }
            if (step==CH_-1){
                float a3 = 0.f;
                if (tid<D_){
                    a3 = bcast_b[tid];
                    #pragma unroll 8
                    for (int k=0;k<D_;k++) a3 += wsv[k]*bcast_w[k*D_+tid];
                    redb[tid] = a3;
                }
                __syncthreads();
                for (int sh=64;sh;sh>>=1){ if(tid<sh) redb[tid]+=redb[tid+sh]; __syncthreads(); }
                float mb = redb[0]*(1.0f/D_);
                __syncthreads();
                float dvv = a3-mb;
                if (tid<D_) redb[tid] = dvv*dvv;
                __syncthreads();
                for (int sh=64;sh;sh>>=1){ if(tid<sh) redb[tid]+=redb[tid+sh]; __syncthreads(); }
                float vb = redb[0]*(1.0f/D_);
                if (tid<D_) bcastv[b*D_+tid] = dvv*(1.0f/sqrtf(vb+1e-5f))*wln_g[tid]+wln_b[tid];
            }
            __syncthreads();
        }
    }

    // ---------------- QKV (one pass) + attention + co + cln-LN ----------------
    {
        const int g = tid >> 7, d2 = tid & 127;
        // Q,K,V for all 32 nodes; one weight fetch feeds 4 nodes
        float aK[4], aV[4], aQ[4];
        #pragma unroll
        for (int q=0;q<4;q++){ aK[q]=ck_b[d2]; aV[q]=cv_b[d2]; aQ[q]=cq_b[d2]; }
        #pragma unroll 4
        for (int k=0;k<D_;k++){
            float wq = cq_w[k*D_+d2];
            float wk = ck_w[k*D_+d2];
            float wv = cv_w[k*D_+d2];
            #pragma unroll
            for (int q=0;q<4;q++){
                float x = st[(q*8+g)*D_+k];
                aQ[q] += x*wq; aK[q] += x*wk; aV[q] += x*wv;
            }
        }
        #pragma unroll
        for (int q=0;q<4;q++){
            smem[KT_O+(q*8+g)*129+d2] = aK[q];
            smem[VT_O+(q*8+g)*129+d2] = aV[q];
            smem[QT_O+(q*8+g)*129+d2] = aQ[q];
        }
        __syncthreads();
        // per ni: scores + softmax + msg (msg overwrites QT row n, Q dead after scores)
        for (int ni=0;ni<4;ni++){
            const int n = ni*8+g;
            {
                const int h = d2>>5, m = d2&31;
                float sdot = 0.f;
                #pragma unroll
                for (int j=0;j<HD_;j++) sdot += smem[QT_O+n*129+h*32+j]*smem[KT_O+m*129+h*32+j];
                sdot *= 0.17677669529663687f; // 1/sqrt(32)
                float mx = sdot;
                #pragma unroll
                for (int off=16;off;off>>=1) mx = fmaxf(mx, __shfl_xor(mx, off, 32));
                float e = expf(sdot-mx);
                float Z = e;
                #pragma unroll
                for (int off=16;off;off>>=1) Z += __shfl_xor(Z, off, 32);
                smem[AW_O+g*128+h*32+m] = e/Z;
            }
            __syncthreads();   // scores written; QT row n reads complete
            {
                const int h2 = d2>>5;
                float mm = 0.f;
                #pragma unroll 8
                for (int m2=0;m2<N_;m2++) mm += smem[AW_O+g*128+h2*32+m2]*smem[VT_O+m2*129+d2];
                smem[QT_O+n*129+d2] = mm;   // MSG row n
            }
            __syncthreads();   // AW reads complete before next ni overwrites
        }
        // co pass: all 32 msg rows -> co projection (4 nodes per thread)
        float acc2[4];
        #pragma unroll
        for (int q=0;q<4;q++) acc2[q] = co_b[d2];
        #pragma unroll 4
        for (int k=0;k<D_;k++){
            float w = co_w[k*D_+d2];
            #pragma unroll
            for (int q=0;q<4;q++) acc2[q] += smem[QT_O+(q*8+g)*129+k]*w;
        }
        // residual + LN per node (4 sequential q passes, 2-wave reduce each)
        for (int q=0;q<4;q++){
            const int n = q*8+g;
            float x = st[n*D_+d2] + acc2[q];
            float s1 = x, s2 = x*x;
            #pragma unroll
            for (int off=32;off;off>>=1){
                s1 += __shfl_xor(s1, off, 64);
                s2 += __shfl_xor(s2, off, 64);
            }
            if ((d2&63)==0){
                smem[RED_O + g*4 + (d2>>6)*2    ] = s1;
                smem[RED_O + g*4 + (d2>>6)*2 + 1] = s2;
            }
            __syncthreads();
            s1 = smem[RED_O+g*4]   + smem[RED_O+g*4+2];
            s2 = smem[RED_O+g*4+1] + smem[RED_O+g*4+3];
            float mn  = s1*(1.0f/D_);
            float var = s2*(1.0f/D_) - mn*mn;
            float st2v = (x-mn)*(1.0f/sqrtf(var+1e-5f))*cln_g[d2]+cln_b[d2];
            states2[((size_t)b*N_+n)*D_+d2] = st2v;
            st[n*D_+d2] = st2v;
            __syncthreads();
        }
        // node-mean of states2 for brains' "incoming"
        if (tid < D_){
            float sm_ = 0.f;
            #pragma unroll 4
            for (int n2=0;n2<N_;n2++) sm_ += st[n2*D_+tid];
            meanv[b*D_+tid] = sm_*(1.0f/N_);
        }
    }
}

// -------------------- per-node brain chain, one block per (b,n), 512 thr --------------------
__global__ void __launch_bounds__(512) k_brains(int c,
        const float* __restrict__ states2, const float* __restrict__ bcast,
        const float* __restrict__ meanv,
        const float* __restrict__ P_w, const float* __restrict__ P_b,
        const float* __restrict__ D1_w, const float* __restrict__ D1_b,
        const float* __restrict__ D2_w, const float* __restrict__ D2_b,
        const float* __restrict__ G_w, const float* __restrict__ G_b,
        const float* __restrict__ SM_w, const float* __restrict__ SM_b,
        const float* __restrict__ PR_w, const float* __restrict__ PR_b,
        const float* __restrict__ ln_g, const float* __restrict__ ln_b,
        float* __restrict__ states, float* __restrict__ prediction){
    int blk = blockIdx.x;
    // XCD swizzle: node n always lands on XCD n%8 -> each XCD L2 caches 4 nodes' weights
    int x8 = blk & 7, qq = blk >> 3;
    int n = x8 + 8*(qq & 3), b = qq >> 2;
    int tid = threadIdx.x, d = tid & 127, h = tid >> 7;   // h: 0..3 quarter of K
    __shared__ float pin[3*D_];
    __shared__ float strow[D_];
    __shared__ float part[4*D_];
    __shared__ float din[2*D_];
    __shared__ float gin[2*D_];
    __shared__ float dec[D_], nsv[D_];
    __shared__ float red[512];
    const size_t rowb = ((size_t)b*N_+n)*D_;
    float inc = meanv[b*D_+d];
    if (tid < D_) strow[d] = states2[rowb+d];
    float pr = prediction[rowb+d];   // previous chunk's prediction
    float diff = inc - pr;
    red[tid] = (h==0)? diff*diff : 0.f;
    __syncthreads();
    for (int sh=256;sh;sh>>=1){ if(tid<sh) red[tid]+=red[tid+sh]; __syncthreads(); }
    float pe = red[0]*(1.0f/D_);
    float surprise = (c>0)? sigm(pe*10.0f) : 0.0f;
    float scale = 1.0f + 0.5f*surprise;
    __syncthreads();
    if (h==0){
        pin[d]      = inc*scale;
        pin[D_+d]   = bcast[b*D_+d];
        pin[2*D_+d] = strow[d];
    }
    __syncthreads();
    // P: K=384 (4x96) -> perception (gelu) into din[0:128]
    {
        const float* Wn = P_w + ((size_t)n*384 + h*96)*D_ + d;
        float a=0;
        #pragma unroll 4
        for (int k=0;k<96;k++) a += pin[h*96+k]*Wn[(size_t)k*D_];
        part[h*128+d]=a;
        __syncthreads();
        if (h==0) din[d] = gelu_f(part[d]+part[128+d]+part[256+d]+part[384+d]+P_b[n*D_+d]);
        __syncthreads();
    }
    // SM: K=128 (4x32) -> self_pred into din[128:256]
    {
        const float* Wn = SM_w + ((size_t)n*128 + h*32)*D_ + d;
        float a=0;
        #pragma unroll 4
        for (int k=0;k<32;k++) a += strow[h*32+k]*Wn[(size_t)k*D_];
        part[h*128+d]=a;
        __syncthreads();
        if (h==0) din[D_+d] = part[d]+part[128+d]+part[256+d]+part[384+d]+SM_b[n*D_+d];
        __syncthreads();
    }
    // D1: K=256 (4x64) -> h1 (gelu) into pin[0:128]
    {
        const float* Wn = D1_w + ((size_t)n*256 + h*64)*D_ + d;
        float a=0;
        #pragma unroll 4
        for (int k=0;k<64;k++) a += din[h*64+k]*Wn[(size_t)k*D_];
        part[h*128+d]=a;
        __syncthreads();
        if (h==0) pin[d] = gelu_f(part[d]+part[128+d]+part[256+d]+part[384+d]+D1_b[n*D_+d]);
        __syncthreads();
    }
    // D2: K=128 (4x32) -> decision
    {
        const float* Wn = D2_w + ((size_t)n*128 + h*32)*D_ + d;
        float a=0;
        #pragma unroll 4
        for (int k=0;k<32;k++) a += pin[h*32+k]*Wn[(size_t)k*D_];
        part[h*128+d]=a;
        __syncthreads();
        if (h==0){ float v = part[d]+part[128+d]+part[256+d]+part[384+d]+D2_b[n*D_+d];
                   dec[d]=v; gin[d]=strow[d]; gin[D_+d]=v; }
        __syncthreads();
    }
    // G: K=256 (4x64) -> gate
    {
        const float* Wn = G_w + ((size_t)n*256 + h*64)*D_ + d;
        float a=0;
        #pragma unroll 4
        for (int k=0;k<64;k++) a += gin[h*64+k]*Wn[(size_t)k*D_];
        part[h*128+d]=a;
        __syncthreads();
    }
    // new_states = LN(g*dec + (1-g)*states')
    float gg=0.f, pre=0.f;
    if (h==0){
        gg = sigm(part[d]+part[128+d]+part[256+d]+part[384+d]+G_b[n*D_+d]);
        pre = gg*dec[d] + (1.0f-gg)*strow[d];
    }
    red[tid] = (h==0)? pre : 0.f;
    __syncthreads();
    for (int sh=256;sh;sh>>=1){ if(tid<sh) red[tid]+=red[tid+sh]; __syncthreads(); }
    float mn = red[0]*(1.0f/D_);
    __syncthreads();
    float dv2 = pre-mn;
    red[tid] = (h==0)? dv2*dv2 : 0.f;
    __syncthreads();
    for (int sh=256;sh;sh>>=1){ if(tid<sh) red[tid]+=red[tid+sh]; __syncthreads(); }
    float var = red[0]*(1.0f/D_);
    __syncthreads();
    if (h==0){
        float nv = dv2*(1.0f/sqrtf(var+1e-5f))*ln_g[d]+ln_b[d];
        nsv[d]=nv;
        states[rowb+d]=nv;
    }
    __syncthreads();
    // PR: K=128 (4x32) -> prediction
    {
        const float* Wn = PR_w + ((size_t)n*128 + h*32)*D_ + d;
        float a=0;
        #pragma unroll 4
        for (int k=0;k<32;k++) a += nsv[h*32+k]*Wn[(size_t)k*D_];
        part[h*128+d]=a;
        __syncthreads();
        if (h==0) prediction[rowb+d] = part[d]+part[128+d]+part[256+d]+part[384+d]+PR_b[n*D_+d];
    }
}

// -------------------- f32 -> bf16 --------------------
__global__ void k_tobf16(const float* __restrict__ src, __hip_bfloat16* __restrict__ dst, int nelem){
    int i = blockIdx.x*256 + threadIdx.x;
    int stride = gridDim.x*256;
    for (; i<nelem; i+=stride) dst[i] = __float2bfloat16(src[i]);
}

// -------------------- final logits GEMM: (2048x128) @ (128x32000) + bias --------------------
typedef __attribute__((ext_vector_type(8))) short short8;
typedef __attribute__((ext_vector_type(4))) float f32x4;

__global__ void __launch_bounds__(256) k_gemm(const __hip_bfloat16* __restrict__ A,  // proj bf16, M x 128
                       const __hip_bfloat16* __restrict__ Bv,                        // emb bf16, V x 128
                       const float* __restrict__ out_bias,
                       float* __restrict__ out){
    int vblk = blockIdx.x;   // 125 blocks * 256 v
    int mblk = blockIdx.y;   // 32 blocks * 64 m
    int tid = threadIdx.x;
    int wave = tid >> 6, lane = tid & 63;
    int l16 = lane & 15, quad = lane >> 4;
    int mrow = mblk*64 + wave*16 + l16;
    f32x4 acc[16];
    #pragma unroll
    for (int j=0;j<16;j++){ f32x4 z = {0.f,0.f,0.f,0.f}; acc[j]=z; }
    short8 afr[4];
    const short* Ap = reinterpret_cast<const short*>(A);
    #pragma unroll
    for (int ks=0;ks<4;ks++)
        afr[ks] = *reinterpret_cast<const short8*>(Ap + mrow*128 + ks*32 + quad*8);
    const short* Bp = reinterpret_cast<const short*>(Bv);
    int vcolbase = vblk*256;
    #pragma unroll
    for (int jj=0;jj<16;jj++){
        int v = vcolbase + jj*16 + l16;
        #pragma unroll
        for (int ks=0;ks<4;ks++){
            short8 bfr = *reinterpret_cast<const short8*>(Bp + (size_t)v*128 + ks*32 + quad*8);
            acc[jj] = __builtin_amdgcn_mfma_f32_16x16x32_bf16(afr[ks], bfr, acc[jj], 0,0,0);
        }
    }
    int mbase = mblk*64 + wave*16 + quad*4;
    #pragma unroll
    for (int jj=0;jj<16;jj++){
        int v = vcolbase + jj*16 + l16;
        float bias = out_bias[v];
        #pragma unroll
        for (int r=0;r<4;r++){
            out[(size_t)(mbase+r)*V_ + v] = acc[jj][r] + bias;
        }
    }
}

extern "C" void kernel_launch(void* const* d_in, const int* in_sizes, int n_in,
                              void* d_out, int out_size, void* d_ws, size_t ws_size,
                              hipStream_t stream){
    (void)in_sizes; (void)n_in; (void)out_size; (void)ws_size;
    const int*   idx      = (const int*)  d_in[0];
    const float* emb      = (const float*)d_in[1];
    const float* pos_emb  = (const float*)d_in[2];
    const float* ifc_w    = (const float*)d_in[3];
    const float* ifc_b    = (const float*)d_in[4];
    const float* ifc_g    = (const float*)d_in[5];
    const float* ifc_beta = (const float*)d_in[6];
    const float* sproj_w  = (const float*)d_in[7];
    const float* sproj_b  = (const float*)d_in[8];
    const float* sgate_w  = (const float*)d_in[9];
    const float* sgate_b  = (const float*)d_in[10];
    const float* P_w  = (const float*)d_in[11];
    const float* P_b  = (const float*)d_in[12];
    const float* D1_w = (const float*)d_in[13];
    const float* D1_b = (const float*)d_in[14];
    const float* D2_w = (const float*)d_in[15];
    const float* D2_b = (const float*)d_in[16];
    // d_in[17], d_in[18]: A_w, A_b -- unused by the reference output
    const float* G_w  = (const float*)d_in[19];
    const float* G_b  = (const float*)d_in[20];
    const float* SM_w = (const float*)d_in[21];
    const float* SM_b = (const float*)d_in[22];
    const float* PR_w = (const float*)d_in[23];
    const float* PR_b = (const float*)d_in[24];
    const float* cq_w = (const float*)d_in[25];
    const float* cq_b = (const float*)d_in[26];
    const float* ck_w = (const float*)d_in[27];
    const float* ck_b = (const float*)d_in[28];
    const float* cv_w = (const float*)d_in[29];
    const float* cv_b = (const float*)d_in[30];
    const float* co_w = (const float*)d_in[31];
    const float* co_b = (const float*)d_in[32];
    const float* cln_g = (const float*)d_in[33];
    const float* cln_b = (const float*)d_in[34];
    const float* sal_w = (const float*)d_in[35];
    const float* sal_b = (const float*)d_in[36];
    const float* bcast_w = (const float*)d_in[37];
    const float* bcast_b = (const float*)d_in[38];
    const float* wln_g = (const float*)d_in[39];
    const float* wln_b = (const float*)d_in[40];
    const float* res_w = (const float*)d_in[41];
    const float* res_b = (const float*)d_in[42];
    const float* out_w = (const float*)d_in[43];
    const float* out_b = (const float*)d_in[44];
    const float* out_bias = (const float*)d_in[45];
    const float* ln_g = (const float*)d_in[46];
    const float* ln_b = (const float*)d_in[47];

    float* ws = (float*)d_ws;
    float* states     = ws + 0;          // 32768
    float* prediction = ws + 32768;      // 32768
    float* states2    = ws + 65536;      // 32768
    float* bcastv     = ws + 98304;      // 1024
    float* meanv      = ws + 99328;      // 1024
    float* percepts   = ws + 197632;     // 262144
    float* sensory    = ws + 459776;     // 2097152
    float* sg_sens    = ws + 2556928;    // 2097152
    float* outresb    = ws + 4654080;    // 262144
    float* projb      = ws + 4916224;    // 262144
    __hip_bfloat16* proj_bf = (__hip_bfloat16*)(ws + 5178368);  // 262144 bf16
    __hip_bfloat16* emb_bf  = (__hip_bfloat16*)(ws + 5309440);  // 4096000 bf16

    // zero the carried state (states + prediction are contiguous)
    hipMemsetAsync(states, 0, 2*32768*sizeof(float), stream);

    k_tobf16<<<512,256,0,stream>>>(emb, emb_bf, V_*D_);
    k_percepts<<<B_*T_,128,0,stream>>>(idx, emb, pos_emb, ifc_w, ifc_b, ifc_g, ifc_beta, percepts);
    k_precomp<<<256,256,0,stream>>>(percepts, sproj_w, sproj_b, sgate_w, res_w, res_b, out_w,
                                    sensory, sg_sens, outresb);
    for (int c=0;c<NCHUNK;c++){
        k_fused<<<B_,1024,0,stream>>>(c, sensory, sg_sens, sgate_w, sgate_b, sal_w, sal_b,
                                      out_w, out_b, outresb, bcast_w, bcast_b, wln_g, wln_b,
                                      cq_w,cq_b, ck_w,ck_b, cv_w,cv_b, co_w,co_b, cln_g,cln_b,
                                      states, states2, bcastv, meanv, projb);
        k_brains<<<256,512,0,stream>>>(c, states2, bcastv, meanv, P_w,P_b,D1_w,D1_b,D2_w,D2_b,
                                       G_w,G_b,SM_w,SM_b,PR_w,PR_b, ln_g,ln_b,
                                       states, prediction);
    }
    k_tobf16<<<256,256,0,stream>>>(projb, proj_bf, B_*T_*D_);
    k_gemm<<<dim3(125,32),256,0,stream>>>(proj_bf, emb_bf, out_bias, (float*)d_out);
}

// Round 4
// 3653.291 us; speedup vs baseline: 4.4133x; 1.1767x over previous
//
#include <hip/hip_runtime.h>
#include <hip/hip_bf16.h>

#define B_ 8
#define T_ 256
#define N_ 32
#define D_ 128
#define S_ 8
#define V_ 32000
#define H_ 4
#define HD_ 32
#define NCHUNK 32
#define CH_ 8

__device__ __forceinline__ float gelu_f(float x){
    return 0.5f * x * (1.0f + erff(x * 0.70710678118654752440f));
}
__device__ __forceinline__ float sigm(float x){
    return 1.0f / (1.0f + expf(-x));
}

typedef __attribute__((ext_vector_type(4))) float f32x4v;

// -------------------- percepts = LN(gelu(raw @ ifc_w + b)) --------------------
__global__ void k_percepts(const int* __restrict__ idx, const float* __restrict__ emb,
                           const float* __restrict__ pos_emb, const float* __restrict__ ifc_w,
                           const float* __restrict__ ifc_b, const float* __restrict__ ifc_g,
                           const float* __restrict__ ifc_beta, float* __restrict__ percepts){
    int r = blockIdx.x;          // r = b*T + t
    int t = r % T_;
    int d = threadIdx.x;         // 128 threads
    __shared__ float raw[D_];
    __shared__ float red[D_];
    int tok = idx[r];
    raw[d] = emb[tok*D_ + d] + pos_emb[t*D_ + d];
    __syncthreads();
    float acc = ifc_b[d];
    #pragma unroll 8
    for (int k=0;k<D_;k++) acc += raw[k]*ifc_w[k*D_+d];
    float x = gelu_f(acc);
    red[d] = x; __syncthreads();
    for (int s=64;s>0;s>>=1){ if(d<s) red[d]+=red[d+s]; __syncthreads(); }
    float m = red[0]*(1.0f/D_); __syncthreads();
    float dv = x-m; red[d] = dv*dv; __syncthreads();
    for (int s=64;s>0;s>>=1){ if(d<s) red[d]+=red[d+s]; __syncthreads(); }
    float var = red[0]*(1.0f/D_);
    percepts[r*D_ + d] = dv * (1.0f/sqrtf(var + 1e-5f)) * ifc_g[d] + ifc_beta[d];
}

// ------ hoisted precompute: sensory, sgate-sensory-part, residual->out contribution ------
__global__ void __launch_bounds__(256) k_precomp(const float* __restrict__ percepts,
                          const float* __restrict__ sproj_w, const float* __restrict__ sproj_b,
                          const float* __restrict__ sgate_w,
                          const float* __restrict__ res_w, const float* __restrict__ res_b,
                          const float* __restrict__ out_w,
                          float* __restrict__ sensory, float* __restrict__ sg_sens,
                          float* __restrict__ outres){
    int blk = blockIdx.x;     // 256: b*32 + c
    int b = blk >> 5, c = blk & 31;
    int tid = threadIdx.x;    // 256
    __shared__ float p[CH_][D_];
    __shared__ float sens[CH_][S_*D_];
    __shared__ float resid[CH_][D_];
    int tbase = b*T_ + c*CH_;
    for (int i = tid; i < CH_*D_; i += 256) p[i>>7][i&127] = percepts[(tbase + (i>>7))*D_ + (i&127)];
    __syncthreads();
    for (int q=0;q<4;q++){
        int sd = tid + 256*q;
        float acc[CH_];
        #pragma unroll
        for(int i=0;i<CH_;i++) acc[i] = sproj_b[sd];
        for (int k=0;k<D_;k++){
            float w = sproj_w[k*(S_*D_) + sd];
            #pragma unroll
            for(int i=0;i<CH_;i++) acc[i] += p[i][k]*w;
        }
        #pragma unroll
        for(int i=0;i<CH_;i++){
            sens[i][sd] = acc[i];
            sensory[(size_t)(tbase+i)*(S_*D_) + sd] = acc[i];
        }
    }
    __syncthreads();
    {
        int d = tid & 127, h = tid >> 7;   // h: i-half
        float acc[4][S_];
        #pragma unroll
        for(int ii=0;ii<4;ii++)
            #pragma unroll
            for(int s=0;s<S_;s++) acc[ii][s]=0.f;
        for (int k=0;k<D_;k++){
            float w = sgate_w[(D_+k)*D_ + d];
            #pragma unroll
            for(int ii=0;ii<4;ii++){
                int i = h*4+ii;
                #pragma unroll
                for(int s=0;s<S_;s++) acc[ii][s] += sens[i][s*D_+k]*w;
            }
        }
        for(int ii=0;ii<4;ii++){ int i=h*4+ii;
            for(int s=0;s<S_;s++) sg_sens[((size_t)(tbase+i)*S_+s)*D_ + d] = acc[ii][s];
        }
    }
    __syncthreads();
    {
        int d = tid & 127, h = tid>>7;
        float acc[4];
        #pragma unroll
        for(int ii=0;ii<4;ii++) acc[ii]=res_b[d];
        for(int k=0;k<D_;k++){
            float w = res_w[k*D_+d];
            #pragma unroll
            for(int ii=0;ii<4;ii++) acc[ii] += p[h*4+ii][k]*w;
        }
        for(int ii=0;ii<4;ii++) resid[h*4+ii][d]=acc[ii];
    }
    __syncthreads();
    {
        int d = tid & 127, h = tid>>7;
        float acc[4];
        #pragma unroll
        for(int ii=0;ii<4;ii++) acc[ii]=0.f;
        for(int k=0;k<D_;k++){
            float w = out_w[(D_+k)*D_ + d];
            #pragma unroll
            for(int ii=0;ii<4;ii++) acc[ii] += resid[h*4+ii][k]*w;
        }
        for(int ii=0;ii<4;ii++) outres[(size_t)(tbase+h*4+ii)*D_ + d] = acc[ii];
    }
}

// ============ fused per-chunk kernel: scan (8 steps) + QKV + attention + cln-LN ============
// one block per batch b, 1024 threads.
// LDS layout (floats):
#define ST_O   0        // 4096  : states 32x128
#define SGW_O  4096     // 16384 : staged sgate_w[128][128]
#define KT_O   20480    // 4128  : K rows 32x129     (scan: ns[1024])
#define VT_O   24608    // 4128  : V rows 32x129
#define QT_O   28736    // 4128  : Q rows -> MSG rows (scan: salv/wtsv live at +128..+191)
#define AW_O   32864    // 1024  : attn weights / scan: wsv_all[8][128]
#define RED_O  33888    // 64    : LN partial sums
#define SMEM_A 33952    // 135.8 KB (gfx950 allows up to 160 KB/workgroup)

__global__ void __launch_bounds__(1024) k_fused(int c,
        const float* __restrict__ sensory, const float* __restrict__ sg_sens,
        const float* __restrict__ sgate_w, const float* __restrict__ sgate_b,
        const float* __restrict__ sal_w, const float* __restrict__ sal_b,
        const float* __restrict__ out_w, const float* __restrict__ out_b,
        const float* __restrict__ outres,
        const float* __restrict__ bcast_w, const float* __restrict__ bcast_b,
        const float* __restrict__ wln_g, const float* __restrict__ wln_b,
        const float* __restrict__ cq_w, const float* __restrict__ cq_b,
        const float* __restrict__ ck_w, const float* __restrict__ ck_b,
        const float* __restrict__ cv_w, const float* __restrict__ cv_b,
        const float* __restrict__ co_w, const float* __restrict__ co_b,
        const float* __restrict__ cln_g, const float* __restrict__ cln_b,
        const float* __restrict__ states, float* __restrict__ states2,
        float* __restrict__ bcastv, float* __restrict__ meanv,
        float* __restrict__ projb){
    const int b = blockIdx.x;
    const int tid = threadIdx.x;
    __shared__ float smem[SMEM_A];
    float* st  = &smem[ST_O];
    float* sgw = &smem[SGW_O];
    float* ns   = &smem[KT_O];
    float* salv = &smem[QT_O+128];
    float* wtsv = &smem[QT_O+160];
    float* wall = &smem[AW_O];       // wsv_all[8][128]
    float* red  = &smem[RED_O];

    for (int i=tid;i<N_*D_;i+=1024) st[i] = states[b*N_*D_+i];
    // stage sgate_w into LDS (same [k][d] layout as global)
    {
        const f32x4v* gw = reinterpret_cast<const f32x4v*>(sgate_w);
        f32x4v* lw = reinterpret_cast<f32x4v*>(sgw);
        for (int i=tid;i<D_*D_/4;i+=1024) lw[i] = gw[i];
    }
    __syncthreads();

    // hoisted sal for constant nodes 8..31 (unchanged during the whole chunk)
    if (tid < 384){
        int nn = 8 + (tid>>4), l = tid&15;
        float pa = 0.f;
        #pragma unroll
        for (int j=0;j<8;j++) pa += st[nn*D_ + l + 16*j]*sal_w[l+16*j];
        #pragma unroll
        for (int off=8;off;off>>=1) pa += __shfl_down(pa, off, 16);
        if (l==0) salv[nn] = pa + sal_b[0];
    }
    __syncthreads();

    // ---------------- scan: 8 timesteps, 4 phases each ----------------
    {
        const int s = tid >> 7, d = tid & 127;
        const float sgb = sgate_b[d];
        const float* stp = &st[s*D_];
        size_t gbase = ((size_t)(b*T_ + c*CH_)*S_ + s)*D_ + d;
        float sgs = sg_sens[gbase], sv = sensory[gbase];
        for (int step=0; step<CH_; step++){
            float sgs_n=0.f, sv_n=0.f;
            if (step < CH_-1){
                sgs_n = sg_sens[gbase + (size_t)(step+1)*(S_*D_)];
                sv_n  = sensory[gbase + (size_t)(step+1)*(S_*D_)];
            }
            // phase A: gate dot (LDS) + new state
            float acc = 0.f;
            #pragma unroll 8
            for (int k=0;k<D_;k++) acc += stp[k]*sgw[k*D_+d];
            acc += sgs + sgb;
            float sg = sigm(acc);
            ns[tid] = sg*stp[d] + (1.0f-sg)*sv;
            __syncthreads();
            // phase B: commit state + sal over the 8 changed nodes (reads ns)
            st[tid] = ns[tid];
            if (tid < 128){
                int nn = tid>>4, l = tid&15;
                float pa = 0.f;
                #pragma unroll
                for (int j=0;j<8;j++) pa += ns[nn*D_ + l + 16*j]*sal_w[l+16*j];
                #pragma unroll
                for (int off=8;off;off>>=1) pa += __shfl_down(pa, off, 16);
                if (l==0) salv[nn] = pa + sal_b[0];
            }
            __syncthreads();
            // phase C: softmax over 32 sal values
            if (tid < 64){
                float v = (tid<N_)? salv[tid]*5.0f : -1e30f;
                float m = v;
                #pragma unroll
                for (int off=32;off;off>>=1) m = fmaxf(m, __shfl_xor(m, off, 64));
                float e = (tid<N_)? expf(v-m) : 0.f;
                float Z = e;
                #pragma unroll
                for (int off=32;off;off>>=1) Z += __shfl_xor(Z, off, 64);
                if (tid<N_) wtsv[tid] = e/Z;
            }
            __syncthreads();
            // phase D: workspace vector, stored for deferred out-projection
            if (tid < D_){
                float w = 0.f;
                #pragma unroll 4
                for (int n=0;n<N_;n++) w += wtsv[n]*st[n*D_+tid];
                wall[step*D_+tid] = w;
            }
            __syncthreads();
            sgs = sgs_n; sv = sv_n;
        }
    }

    // ---------------- deferred out-projection: all 8 steps in one batch ----------------
    {
        const int stp8 = tid >> 7, dd = tid & 127;
        const int tg = b*T_ + c*CH_ + stp8;
        float a2 = out_b[dd] + outres[(size_t)tg*D_+dd];
        const float* wsp = &wall[stp8*D_];
        #pragma unroll 8
        for (int k=0;k<D_;k++) a2 += wsp[k]*out_w[k*D_+dd];
        projb[(size_t)tg*D_+dd] = gelu_f(a2);
    }
    // bcast = LN(wsv[7] @ bcast_w + b) -- one-pass LN via 2-wave shuffles
    float a3 = 0.f;
    if (tid < D_){
        a3 = bcast_b[tid];
        #pragma unroll 8
        for (int k=0;k<D_;k++) a3 += wall[7*D_+k]*bcast_w[k*D_+tid];
        float s1 = a3, s2 = a3*a3;
        #pragma unroll
        for (int off=32;off;off>>=1){ s1 += __shfl_xor(s1,off,64); s2 += __shfl_xor(s2,off,64); }
        if ((tid&63)==0){ red[(tid>>6)*2]=s1; red[(tid>>6)*2+1]=s2; }
    }
    __syncthreads();
    if (tid < D_){
        float s1 = red[0]+red[2], s2 = red[1]+red[3];
        float mb = s1*(1.0f/D_);
        float vb = s2*(1.0f/D_) - mb*mb;
        bcastv[b*D_+tid] = (a3-mb)*(1.0f/sqrtf(vb+1e-5f))*wln_g[tid]+wln_b[tid];
    }

    // ---------------- QKV (one pass) + attention + co + cln-LN ----------------
    {
        const int g = tid >> 7, d2 = tid & 127;
        // Q,K,V for all 32 nodes; one weight fetch feeds 4 nodes
        float aK[4], aV[4], aQ[4];
        #pragma unroll
        for (int q=0;q<4;q++){ aK[q]=ck_b[d2]; aV[q]=cv_b[d2]; aQ[q]=cq_b[d2]; }
        #pragma unroll 4
        for (int k=0;k<D_;k++){
            float wq = cq_w[k*D_+d2];
            float wk = ck_w[k*D_+d2];
            float wv = cv_w[k*D_+d2];
            #pragma unroll
            for (int q=0;q<4;q++){
                float x = st[(q*8+g)*D_+k];
                aQ[q] += x*wq; aK[q] += x*wk; aV[q] += x*wv;
            }
        }
        #pragma unroll
        for (int q=0;q<4;q++){
            smem[KT_O+(q*8+g)*129+d2] = aK[q];
            smem[VT_O+(q*8+g)*129+d2] = aV[q];
            smem[QT_O+(q*8+g)*129+d2] = aQ[q];
        }
        __syncthreads();
        // per ni: scores + softmax + msg (msg overwrites QT row n, Q dead after scores)
        for (int ni=0;ni<4;ni++){
            const int n = ni*8+g;
            {
                const int h = d2>>5, m = d2&31;
                float sdot = 0.f;
                #pragma unroll
                for (int j=0;j<HD_;j++) sdot += smem[QT_O+n*129+h*32+j]*smem[KT_O+m*129+h*32+j];
                sdot *= 0.17677669529663687f; // 1/sqrt(32)
                float mx = sdot;
                #pragma unroll
                for (int off=16;off;off>>=1) mx = fmaxf(mx, __shfl_xor(mx, off, 32));
                float e = expf(sdot-mx);
                float Z = e;
                #pragma unroll
                for (int off=16;off;off>>=1) Z += __shfl_xor(Z, off, 32);
                smem[AW_O+g*128+h*32+m] = e/Z;
            }
            __syncthreads();   // scores written; QT row n reads complete
            {
                const int h2 = d2>>5;
                float mm = 0.f;
                #pragma unroll 8
                for (int m2=0;m2<N_;m2++) mm += smem[AW_O+g*128+h2*32+m2]*smem[VT_O+m2*129+d2];
                smem[QT_O+n*129+d2] = mm;   // MSG row n
            }
            __syncthreads();   // AW reads complete before next ni overwrites
        }
        // co pass: all 32 msg rows -> co projection (4 nodes per thread)
        float acc2[4];
        #pragma unroll
        for (int q=0;q<4;q++) acc2[q] = co_b[d2];
        #pragma unroll 4
        for (int k=0;k<D_;k++){
            float w = co_w[k*D_+d2];
            #pragma unroll
            for (int q=0;q<4;q++) acc2[q] += smem[QT_O+(q*8+g)*129+k]*w;
        }
        // residual + LN per node (4 sequential q passes, 2-wave reduce each)
        for (int q=0;q<4;q++){
            const int n = q*8+g;
            float x = st[n*D_+d2] + acc2[q];
            float s1 = x, s2 = x*x;
            #pragma unroll
            for (int off=32;off;off>>=1){
                s1 += __shfl_xor(s1, off, 64);
                s2 += __shfl_xor(s2, off, 64);
            }
            if ((d2&63)==0){
                smem[RED_O + g*4 + (d2>>6)*2    ] = s1;
                smem[RED_O + g*4 + (d2>>6)*2 + 1] = s2;
            }
            __syncthreads();
            s1 = smem[RED_O+g*4]   + smem[RED_O+g*4+2];
            s2 = smem[RED_O+g*4+1] + smem[RED_O+g*4+3];
            float mn  = s1*(1.0f/D_);
            float var = s2*(1.0f/D_) - mn*mn;
            float st2v = (x-mn)*(1.0f/sqrtf(var+1e-5f))*cln_g[d2]+cln_b[d2];
            states2[((size_t)b*N_+n)*D_+d2] = st2v;
            st[n*D_+d2] = st2v;
            __syncthreads();
        }
        // node-mean of states2 for brains' "incoming"
        if (tid < D_){
            float sm_ = 0.f;
            #pragma unroll 4
            for (int n2=0;n2<N_;n2++) sm_ += st[n2*D_+tid];
            meanv[b*D_+tid] = sm_*(1.0f/N_);
        }
    }
}

// -------------------- per-node brain chain, one block per (b,n), 1024 thr --------------------
__global__ void __launch_bounds__(1024) k_brains(int c,
        const float* __restrict__ states2, const float* __restrict__ bcast,
        const float* __restrict__ meanv,
        const float* __restrict__ P_w, const float* __restrict__ P_b,
        const float* __restrict__ D1_w, const float* __restrict__ D1_b,
        const float* __restrict__ D2_w, const float* __restrict__ D2_b,
        const float* __restrict__ G_w, const float* __restrict__ G_b,
        const float* __restrict__ SM_w, const float* __restrict__ SM_b,
        const float* __restrict__ PR_w, const float* __restrict__ PR_b,
        const float* __restrict__ ln_g, const float* __restrict__ ln_b,
        float* __restrict__ states, float* __restrict__ prediction){
    int blk = blockIdx.x;
    // XCD swizzle: node n always lands on XCD n%8 -> each XCD L2 caches 4 nodes' weights
    int x8 = blk & 7, qq = blk >> 3;
    int n = x8 + 8*(qq & 3), b = qq >> 2;
    int tid = threadIdx.x, d = tid & 127, h = tid >> 7;   // h: 0..7 eighth of K
    __shared__ float strow[D_], incv[D_], bcv[D_];
    __shared__ float din[2*D_];
    __shared__ float h1v[D_], dec[D_], nsv[D_];
    __shared__ float part[1024];
    __shared__ float red[8];
    const size_t rowb = ((size_t)b*N_+n)*D_;
    // stage inputs + pe partial (2-wave shuffle)
    if (h==0){
        float sv = states2[rowb+d]; strow[d]=sv;
        float iv = meanv[b*D_+d];   incv[d]=iv;
        float pr = prediction[rowb+d];
        float df = iv - pr;
        float s1 = df*df;
        #pragma unroll
        for (int off=32;off;off>>=1) s1 += __shfl_xor(s1, off, 64);
        if ((tid&63)==0) red[tid>>6] = s1;
    } else if (h==1){
        bcv[d] = bcast[b*D_+d];
    }
    __syncthreads();
    float pe = (red[0]+red[1])*(1.0f/D_);
    float scale = (c>0)? (1.0f + 0.5f*sigm(pe*10.0f)) : 1.0f;
    // concurrent dots: P (K=384, h0..5: scale factored out of the inc block) | SM (K=128, h6..7)
    {
        float a = 0.f;
        if (h < 6){
            int src = h >> 1;                  // 0: incoming, 1: broadcast, 2: states
            const float* xv = (src==0)? incv : (src==1)? bcv : strow;
            int k0 = (h&1)*64;
            const float* Wn = P_w + ((size_t)n*384 + src*128 + k0)*D_ + d;
            #pragma unroll 4
            for (int k=0;k<64;k++) a += xv[k0+k]*Wn[(size_t)k*D_];
        } else {
            int k0 = (h&1)*64;
            const float* Wn = SM_w + ((size_t)n*128 + k0)*D_ + d;
            #pragma unroll 4
            for (int k=0;k<64;k++) a += strow[k0+k]*Wn[(size_t)k*D_];
        }
        part[tid] = a;
    }
    __syncthreads();
    if (h==0){
        float v = scale*(part[d]+part[128+d]) + part[256+d]+part[384+d]+part[512+d]+part[640+d] + P_b[n*D_+d];
        din[d] = gelu_f(v);
    } else if (h==1){
        din[D_+d] = part[768+d]+part[896+d] + SM_b[n*D_+d];
    }
    __syncthreads();
    // D1: K=256 (8x32) -> h1 (gelu)
    {
        const float* Wn = D1_w + ((size_t)n*256 + h*32)*D_ + d;
        float a=0;
        #pragma unroll 4
        for (int k=0;k<32;k++) a += din[h*32+k]*Wn[(size_t)k*D_];
        part[tid]=a;
    }
    __syncthreads();
    if (h==0){
        float v = part[d]+part[128+d]+part[256+d]+part[384+d]+part[512+d]+part[640+d]+part[768+d]+part[896+d] + D1_b[n*D_+d];
        h1v[d] = gelu_f(v);
    }
    __syncthreads();
    // D2: K=128 (8x16) -> decision
    {
        const float* Wn = D2_w + ((size_t)n*128 + h*16)*D_ + d;
        float a=0;
        #pragma unroll
        for (int k=0;k<16;k++) a += h1v[h*16+k]*Wn[(size_t)k*D_];
        part[tid]=a;
    }
    __syncthreads();
    if (h==0){
        dec[d] = part[d]+part[128+d]+part[256+d]+part[384+d]+part[512+d]+part[640+d]+part[768+d]+part[896+d] + D2_b[n*D_+d];
    }
    __syncthreads();
    // G: K=256: rows 0..127 = states', rows 128..255 = decision
    {
        float a=0;
        if (h < 4){
            const float* Wn = G_w + ((size_t)n*256 + h*32)*D_ + d;
            #pragma unroll 4
            for (int k=0;k<32;k++) a += strow[h*32+k]*Wn[(size_t)k*D_];
        } else {
            const float* Wn = G_w + ((size_t)n*256 + 128 + (h-4)*32)*D_ + d;
            #pragma unroll 4
            for (int k=0;k<32;k++) a += dec[(h-4)*32+k]*Wn[(size_t)k*D_];
        }
        part[tid]=a;
    }
    __syncthreads();
    // gate + pre-LN value (tid<128, 2-wave shuffle LN)
    if (h==0){
        float gg = sigm(part[d]+part[128+d]+part[256+d]+part[384+d]+part[512+d]+part[640+d]+part[768+d]+part[896+d] + G_b[n*D_+d]);
        float pre = gg*dec[d] + (1.0f-gg)*strow[d];
        nsv[d] = pre;       // temp
        float s1 = pre, s2 = pre*pre;
        #pragma unroll
        for (int off=32;off;off>>=1){ s1 += __shfl_xor(s1, off, 64); s2 += __shfl_xor(s2, off, 64); }
        if ((tid&63)==0){ red[(tid>>6)*2]=s1; red[(tid>>6)*2+1]=s2; }
    }
    __syncthreads();
    if (h==0){
        float s1 = red[0]+red[2], s2 = red[1]+red[3];
        float mn = s1*(1.0f/D_);
        float var = s2*(1.0f/D_) - mn*mn;
        float pre = nsv[d];
        float nv = (pre-mn)*(1.0f/sqrtf(var+1e-5f))*ln_g[d]+ln_b[d];
        nsv[d]=nv;
        states[rowb+d]=nv;
    }
    __syncthreads();
    // PR: K=128 (8x16) -> prediction
    {
        const float* Wn = PR_w + ((size_t)n*128 + h*16)*D_ + d;
        float a=0;
        #pragma unroll
        for (int k=0;k<16;k++) a += nsv[h*16+k]*Wn[(size_t)k*D_];
        part[tid]=a;
    }
    __syncthreads();
    if (h==0){
        prediction[rowb+d] = part[d]+part[128+d]+part[256+d]+part[384+d]+part[512+d]+part[640+d]+part[768+d]+part[896+d] + PR_b[n*D_+d];
    }
}

// -------------------- f32 -> bf16 --------------------
__global__ void k_tobf16(const float* __restrict__ src, __hip_bfloat16* __restrict__ dst, int nelem){
    int i = blockIdx.x*256 + threadIdx.x;
    int stride = gridDim.x*256;
    for (; i<nelem; i+=stride) dst[i] = __float2bfloat16(src[i]);
}

// -------------------- final logits GEMM: (2048x128) @ (128x32000) + bias --------------------
typedef __attribute__((ext_vector_type(8))) short short8;
typedef __attribute__((ext_vector_type(4))) float f32x4;

__global__ void __launch_bounds__(256) k_gemm(const __hip_bfloat16* __restrict__ A,  // proj bf16, M x 128
                       const __hip_bfloat16* __restrict__ Bv,                        // emb bf16, V x 128
                       const float* __restrict__ out_bias,
                       float* __restrict__ out){
    int vblk = blockIdx.x;   // 125 blocks * 256 v
    int mblk = blockIdx.y;   // 32 blocks * 64 m
    int tid = threadIdx.x;
    int wave = tid >> 6, lane = tid & 63;
    int l16 = lane & 15, quad = lane >> 4;
    int mrow = mblk*64 + wave*16 + l16;
    f32x4 acc[16];
    #pragma unroll
    for (int j=0;j<16;j++){ f32x4 z = {0.f,0.f,0.f,0.f}; acc[j]=z; }
    short8 afr[4];
    const short* Ap = reinterpret_cast<const short*>(A);
    #pragma unroll
    for (int ks=0;ks<4;ks++)
        afr[ks] = *reinterpret_cast<const short8*>(Ap + mrow*128 + ks*32 + quad*8);
    const short* Bp = reinterpret_cast<const short*>(Bv);
    int vcolbase = vblk*256;
    #pragma unroll
    for (int jj=0;jj<16;jj++){
        int v = vcolbase + jj*16 + l16;
        #pragma unroll
        for (int ks=0;ks<4;ks++){
            short8 bfr = *reinterpret_cast<const short8*>(Bp + (size_t)v*128 + ks*32 + quad*8);
            acc[jj] = __builtin_amdgcn_mfma_f32_16x16x32_bf16(afr[ks], bfr, acc[jj], 0,0,0);
        }
    }
    int mbase = mblk*64 + wave*16 + quad*4;
    #pragma unroll
    for (int jj=0;jj<16;jj++){
        int v = vcolbase + jj*16 + l16;
        float bias = out_bias[v];
        #pragma unroll
        for (int r=0;r<4;r++){
            out[(size_t)(mbase+r)*V_ + v] = acc[jj][r] + bias;
        }
    }
}

extern "C" void kernel_launch(void* const* d_in, const int* in_sizes, int n_in,
                              void* d_out, int out_size, void* d_ws, size_t ws_size,
                              hipStream_t stream){
    (void)in_sizes; (void)n_in; (void)out_size; (void)ws_size;
    const int*   idx      = (const int*)  d_in[0];
    const float* emb      = (const float*)d_in[1];
    const float* pos_emb  = (const float*)d_in[2];
    const float* ifc_w    = (const float*)d_in[3];
    const float* ifc_b    = (const float*)d_in[4];
    const float* ifc_g    = (const float*)d_in[5];
    const float* ifc_beta = (const float*)d_in[6];
    const float* sproj_w  = (const float*)d_in[7];
    const float* sproj_b  = (const float*)d_in[8];
    const float* sgate_w  = (const float*)d_in[9];
    const float* sgate_b  = (const float*)d_in[10];
    const float* P_w  = (const float*)d_in[11];
    const float* P_b  = (const float*)d_in[12];
    const float* D1_w = (const float*)d_in[13];
    const float* D1_b = (const float*)d_in[14];
    const float* D2_w = (const float*)d_in[15];
    const float* D2_b = (const float*)d_in[16];
    // d_in[17], d_in[18]: A_w, A_b -- unused by the reference output
    const float* G_w  = (const float*)d_in[19];
    const float* G_b  = (const float*)d_in[20];
    const float* SM_w = (const float*)d_in[21];
    const float* SM_b = (const float*)d_in[22];
    const float* PR_w = (const float*)d_in[23];
    const float* PR_b = (const float*)d_in[24];
    const float* cq_w = (const float*)d_in[25];
    const float* cq_b = (const float*)d_in[26];
    const float* ck_w = (const float*)d_in[27];
    const float* ck_b = (const float*)d_in[28];
    const float* cv_w = (const float*)d_in[29];
    const float* cv_b = (const float*)d_in[30];
    const float* co_w = (const float*)d_in[31];
    const float* co_b = (const float*)d_in[32];
    const float* cln_g = (const float*)d_in[33];
    const float* cln_b = (const float*)d_in[34];
    const float* sal_w = (const float*)d_in[35];
    const float* sal_b = (const float*)d_in[36];
    const float* bcast_w = (const float*)d_in[37];
    const float* bcast_b = (const float*)d_in[38];
    const float* wln_g = (const float*)d_in[39];
    const float* wln_b = (const float*)d_in[40];
    const float* res_w = (const float*)d_in[41];
    const float* res_b = (const float*)d_in[42];
    const float* out_w = (const float*)d_in[43];
    const float* out_b = (const float*)d_in[44];
    const float* out_bias = (const float*)d_in[45];
    const float* ln_g = (const float*)d_in[46];
    const float* ln_b = (const float*)d_in[47];

    float* ws = (float*)d_ws;
    float* states     = ws + 0;          // 32768
    float* prediction = ws + 32768;      // 32768
    float* states2    = ws + 65536;      // 32768
    float* bcastv     = ws + 98304;      // 1024
    float* meanv      = ws + 99328;      // 1024
    float* percepts   = ws + 197632;     // 262144
    float* sensory    = ws + 459776;     // 2097152
    float* sg_sens    = ws + 2556928;    // 2097152
    float* outresb    = ws + 4654080;    // 262144
    float* projb      = ws + 4916224;    // 262144
    __hip_bfloat16* proj_bf = (__hip_bfloat16*)(ws + 5178368);  // 262144 bf16
    __hip_bfloat16* emb_bf  = (__hip_bfloat16*)(ws + 5309440);  // 4096000 bf16

    // zero the carried state (states + prediction are contiguous)
    hipMemsetAsync(states, 0, 2*32768*sizeof(float), stream);

    k_tobf16<<<512,256,0,stream>>>(emb, emb_bf, V_*D_);
    k_percepts<<<B_*T_,128,0,stream>>>(idx, emb, pos_emb, ifc_w, ifc_b, ifc_g, ifc_beta, percepts);
    k_precomp<<<256,256,0,stream>>>(percepts, sproj_w, sproj_b, sgate_w, res_w, res_b, out_w,
                                    sensory, sg_sens, outresb);
    for (int c=0;c<NCHUNK;c++){
        k_fused<<<B_,1024,0,stream>>>(c, sensory, sg_sens, sgate_w, sgate_b, sal_w, sal_b,
                                      out_w, out_b, outresb, bcast_w, bcast_b, wln_g, wln_b,
                                      cq_w,cq_b, ck_w,ck_b, cv_w,cv_b, co_w,co_b, cln_g,cln_b,
                                      states, states2, bcastv, meanv, projb);
        k_brains<<<256,1024,0,stream>>>(c, states2, bcastv, meanv, P_w,P_b,D1_w,D1_b,D2_w,D2_b,
                                        G_w,G_b,SM_w,SM_b,PR_w,PR_b, ln_g,ln_b,
                                        states, prediction);
    }
    k_tobf16<<<256,256,0,stream>>>(projb, proj_bf, B_*T_*D_);
    k_gemm<<<dim3(125,32),256,0,stream>>>(proj_bf, emb_bf, out_bias, (float*)d_out);
}

// Round 5
// 3642.775 us; speedup vs baseline: 4.4260x; 1.0029x over previous
//
#include <hip/hip_runtime.h>
#include <hip/hip_bf16.h>

#define B_ 8
#define T_ 256
#define N_ 32
#define D_ 128
#define S_ 8
#define V_ 32000
#define H_ 4
#define HD_ 32
#define NCHUNK 32
#define CH_ 8

__device__ __forceinline__ float gelu_f(float x){
    return 0.5f * x * (1.0f + erff(x * 0.70710678118654752440f));
}
__device__ __forceinline__ float sigm(float x){
    return 1.0f / (1.0f + expf(-x));
}

typedef __attribute__((ext_vector_type(4))) float f32x4v;

// -------------------- percepts = LN(gelu(raw @ ifc_w + b)) --------------------
__global__ void k_percepts(const int* __restrict__ idx, const float* __restrict__ emb,
                           const float* __restrict__ pos_emb, const float* __restrict__ ifc_w,
                           const float* __restrict__ ifc_b, const float* __restrict__ ifc_g,
                           const float* __restrict__ ifc_beta, float* __restrict__ percepts){
    int r = blockIdx.x;          // r = b*T + t
    int t = r % T_;
    int d = threadIdx.x;         // 128 threads
    __shared__ float raw[D_];
    __shared__ float red[D_];
    int tok = idx[r];
    raw[d] = emb[tok*D_ + d] + pos_emb[t*D_ + d];
    __syncthreads();
    float acc = ifc_b[d];
    #pragma unroll 8
    for (int k=0;k<D_;k++) acc += raw[k]*ifc_w[k*D_+d];
    float x = gelu_f(acc);
    red[d] = x; __syncthreads();
    for (int s=64;s>0;s>>=1){ if(d<s) red[d]+=red[d+s]; __syncthreads(); }
    float m = red[0]*(1.0f/D_); __syncthreads();
    float dv = x-m; red[d] = dv*dv; __syncthreads();
    for (int s=64;s>0;s>>=1){ if(d<s) red[d]+=red[d+s]; __syncthreads(); }
    float var = red[0]*(1.0f/D_);
    percepts[r*D_ + d] = dv * (1.0f/sqrtf(var + 1e-5f)) * ifc_g[d] + ifc_beta[d];
}

// ------ hoisted precompute: sensory, sgate-sensory-part, residual->out contribution ------
__global__ void __launch_bounds__(256) k_precomp(const float* __restrict__ percepts,
                          const float* __restrict__ sproj_w, const float* __restrict__ sproj_b,
                          const float* __restrict__ sgate_w,
                          const float* __restrict__ res_w, const float* __restrict__ res_b,
                          const float* __restrict__ out_w,
                          float* __restrict__ sensory, float* __restrict__ sg_sens,
                          float* __restrict__ outres){
    int blk = blockIdx.x;     // 256: b*32 + c
    int b = blk >> 5, c = blk & 31;
    int tid = threadIdx.x;    // 256
    __shared__ float p[CH_][D_];
    __shared__ float sens[CH_][S_*D_];
    __shared__ float resid[CH_][D_];
    int tbase = b*T_ + c*CH_;
    for (int i = tid; i < CH_*D_; i += 256) p[i>>7][i&127] = percepts[(tbase + (i>>7))*D_ + (i&127)];
    __syncthreads();
    for (int q=0;q<4;q++){
        int sd = tid + 256*q;
        float acc[CH_];
        #pragma unroll
        for(int i=0;i<CH_;i++) acc[i] = sproj_b[sd];
        for (int k=0;k<D_;k++){
            float w = sproj_w[k*(S_*D_) + sd];
            #pragma unroll
            for(int i=0;i<CH_;i++) acc[i] += p[i][k]*w;
        }
        #pragma unroll
        for(int i=0;i<CH_;i++){
            sens[i][sd] = acc[i];
            sensory[(size_t)(tbase+i)*(S_*D_) + sd] = acc[i];
        }
    }
    __syncthreads();
    {
        int d = tid & 127, h = tid >> 7;   // h: i-half
        float acc[4][S_];
        #pragma unroll
        for(int ii=0;ii<4;ii++)
            #pragma unroll
            for(int s=0;s<S_;s++) acc[ii][s]=0.f;
        for (int k=0;k<D_;k++){
            float w = sgate_w[(D_+k)*D_ + d];
            #pragma unroll
            for(int ii=0;ii<4;ii++){
                int i = h*4+ii;
                #pragma unroll
                for(int s=0;s<S_;s++) acc[ii][s] += sens[i][s*D_+k]*w;
            }
        }
        for(int ii=0;ii<4;ii++){ int i=h*4+ii;
            for(int s=0;s<S_;s++) sg_sens[((size_t)(tbase+i)*S_+s)*D_ + d] = acc[ii][s];
        }
    }
    __syncthreads();
    {
        int d = tid & 127, h = tid>>7;
        float acc[4];
        #pragma unroll
        for(int ii=0;ii<4;ii++) acc[ii]=res_b[d];
        for(int k=0;k<D_;k++){
            float w = res_w[k*D_+d];
            #pragma unroll
            for(int ii=0;ii<4;ii++) acc[ii] += p[h*4+ii][k]*w;
        }
        for(int ii=0;ii<4;ii++) resid[h*4+ii][d]=acc[ii];
    }
    __syncthreads();
    {
        int d = tid & 127, h = tid>>7;
        float acc[4];
        #pragma unroll
        for(int ii=0;ii<4;ii++) acc[ii]=0.f;
        for(int k=0;k<D_;k++){
            float w = out_w[(D_+k)*D_ + d];
            #pragma unroll
            for(int ii=0;ii<4;ii++) acc[ii] += resid[h*4+ii][k]*w;
        }
        for(int ii=0;ii<4;ii++) outres[(size_t)(tbase+h*4+ii)*D_ + d] = acc[ii];
    }
}

// ============ per-chunk scan kernel: scan (8 steps) + out-proj + bcast + QKV ============
// one block per batch b, 1024 threads.
#define ST_O   0        // 4096  : states 32x128
#define SGW_O  4096     // 16384 : staged sgate_w[128][128]
#define NS_O   20480    // 1024  : scan double buffer
#define WALL_O 21504    // 1024  : wsv_all[8][128]
#define SALV_O 22528    // 32
#define WTSV_O 22560    // 32
#define RED_O  22592    // 64
#define SMEM_S 22656    // 90.6 KB

__global__ void __launch_bounds__(1024) k_scan(int c,
        const float* __restrict__ sensory, const float* __restrict__ sg_sens,
        const float* __restrict__ sgate_w, const float* __restrict__ sgate_b,
        const float* __restrict__ sal_w, const float* __restrict__ sal_b,
        const float* __restrict__ out_w, const float* __restrict__ out_b,
        const float* __restrict__ outres,
        const float* __restrict__ bcast_w, const float* __restrict__ bcast_b,
        const float* __restrict__ wln_g, const float* __restrict__ wln_b,
        const float* __restrict__ cq_w, const float* __restrict__ cq_b,
        const float* __restrict__ ck_w, const float* __restrict__ ck_b,
        const float* __restrict__ cv_w, const float* __restrict__ cv_b,
        const float* __restrict__ st_in, float* __restrict__ scanA,
        float* __restrict__ bcastv,
        float* __restrict__ Qg, float* __restrict__ Kg, float* __restrict__ Vg,
        float* __restrict__ projb){
    const int b = blockIdx.x;
    const int tid = threadIdx.x;
    __shared__ float smem[SMEM_S];
    float* st   = &smem[ST_O];
    float* sgw  = &smem[SGW_O];
    float* ns   = &smem[NS_O];
    float* wall = &smem[WALL_O];
    float* salv = &smem[SALV_O];
    float* wtsv = &smem[WTSV_O];
    float* red  = &smem[RED_O];

    for (int i=tid;i<N_*D_;i+=1024) st[i] = st_in[(size_t)b*N_*D_+i];
    {
        const f32x4v* gw = reinterpret_cast<const f32x4v*>(sgate_w);
        f32x4v* lw = reinterpret_cast<f32x4v*>(sgw);
        for (int i=tid;i<D_*D_/4;i+=1024) lw[i] = gw[i];
    }
    __syncthreads();

    // hoisted sal for constant nodes 8..31 (unchanged during the whole chunk)
    if (tid < 384){
        int nn = 8 + (tid>>4), l = tid&15;
        float pa = 0.f;
        #pragma unroll
        for (int j=0;j<8;j++) pa += st[nn*D_ + l + 16*j]*sal_w[l+16*j];
        #pragma unroll
        for (int off=8;off;off>>=1) pa += __shfl_down(pa, off, 16);
        if (l==0) salv[nn] = pa + sal_b[0];
    }
    __syncthreads();

    // ---------------- scan: 8 timesteps, 4 phases each ----------------
    {
        const int s = tid >> 7, d = tid & 127;
        const float sgb = sgate_b[d];
        const float* stp = &st[s*D_];
        size_t gbase = ((size_t)(b*T_ + c*CH_)*S_ + s)*D_ + d;
        float sgs = sg_sens[gbase], sv = sensory[gbase];
        for (int step=0; step<CH_; step++){
            float sgs_n=0.f, sv_n=0.f;
            if (step < CH_-1){
                sgs_n = sg_sens[gbase + (size_t)(step+1)*(S_*D_)];
                sv_n  = sensory[gbase + (size_t)(step+1)*(S_*D_)];
            }
            // phase A: gate dot (LDS) + new state
            float acc = 0.f;
            #pragma unroll 8
            for (int k=0;k<D_;k++) acc += stp[k]*sgw[k*D_+d];
            acc += sgs + sgb;
            float sg = sigm(acc);
            ns[tid] = sg*stp[d] + (1.0f-sg)*sv;
            __syncthreads();
            // phase B: commit state + sal over the 8 changed nodes
            st[tid] = ns[tid];
            if (tid < 128){
                int nn = tid>>4, l = tid&15;
                float pa = 0.f;
                #pragma unroll
                for (int j=0;j<8;j++) pa += ns[nn*D_ + l + 16*j]*sal_w[l+16*j];
                #pragma unroll
                for (int off=8;off;off>>=1) pa += __shfl_down(pa, off, 16);
                if (l==0) salv[nn] = pa + sal_b[0];
            }
            __syncthreads();
            // phase C: softmax over 32 sal values
            if (tid < 64){
                float v = (tid<N_)? salv[tid]*5.0f : -1e30f;
                float m = v;
                #pragma unroll
                for (int off=32;off;off>>=1) m = fmaxf(m, __shfl_xor(m, off, 64));
                float e = (tid<N_)? expf(v-m) : 0.f;
                float Z = e;
                #pragma unroll
                for (int off=32;off;off>>=1) Z += __shfl_xor(Z, off, 64);
                if (tid<N_) wtsv[tid] = e/Z;
            }
            __syncthreads();
            // phase D: workspace vector
            if (tid < D_){
                float w = 0.f;
                #pragma unroll 4
                for (int n=0;n<N_;n++) w += wtsv[n]*st[n*D_+tid];
                wall[step*D_+tid] = w;
            }
            __syncthreads();
            sgs = sgs_n; sv = sv_n;
        }
    }

    // ---------------- deferred out-projection: all 8 steps at once ----------------
    {
        const int stp8 = tid >> 7, dd = tid & 127;
        const int tg = b*T_ + c*CH_ + stp8;
        float a2 = out_b[dd] + outres[(size_t)tg*D_+dd];
        const float* wsp = &wall[stp8*D_];
        #pragma unroll 8
        for (int k=0;k<D_;k++) a2 += wsp[k]*out_w[k*D_+dd];
        projb[(size_t)tg*D_+dd] = gelu_f(a2);
    }
    // bcast = LN(wsv[7] @ bcast_w + b)
    float a3 = 0.f;
    if (tid < D_){
        a3 = bcast_b[tid];
        #pragma unroll 8
        for (int k=0;k<D_;k++) a3 += wall[7*D_+k]*bcast_w[k*D_+tid];
        float s1 = a3, s2 = a3*a3;
        #pragma unroll
        for (int off=32;off;off>>=1){ s1 += __shfl_xor(s1,off,64); s2 += __shfl_xor(s2,off,64); }
        if ((tid&63)==0){ red[(tid>>6)*2]=s1; red[(tid>>6)*2+1]=s2; }
    }
    __syncthreads();
    if (tid < D_){
        float s1 = red[0]+red[2], s2 = red[1]+red[3];
        float mb = s1*(1.0f/D_);
        float vb = s2*(1.0f/D_) - mb*mb;
        bcastv[b*D_+tid] = (a3-mb)*(1.0f/sqrtf(vb+1e-5f))*wln_g[tid]+wln_b[tid];
    }
    // post-scan states rows 0..7 for attnbrains
    scanA[b*S_*D_ + tid] = st[tid];
    // ---------------- QKV for all 32 nodes -> global ----------------
    {
        const int g = tid >> 7, d2 = tid & 127;
        float aK[4], aV[4], aQ[4];
        #pragma unroll
        for (int q=0;q<4;q++){ aK[q]=ck_b[d2]; aV[q]=cv_b[d2]; aQ[q]=cq_b[d2]; }
        #pragma unroll 4
        for (int k=0;k<D_;k++){
            float wq = cq_w[k*D_+d2];
            float wk = ck_w[k*D_+d2];
            float wv = cv_w[k*D_+d2];
            #pragma unroll
            for (int q=0;q<4;q++){
                float x = st[(q*8+g)*D_+k];
                aQ[q] += x*wq; aK[q] += x*wk; aV[q] += x*wv;
            }
        }
        #pragma unroll
        for (int q=0;q<4;q++){
            int nb = b*N_ + q*8+g;
            Qg[nb*D_+d2]=aQ[q]; Kg[nb*D_+d2]=aK[q]; Vg[nb*D_+d2]=aV[q];
        }
    }
}

// ======== per-(b,n) attention + brains kernel, 256 blocks x 1024 threads ========
// attention/co/cln-LN computed for ALL 32 nodes (redundant per block) so the
// node-mean ("incoming") is available in-block; then brains for own node n.
#define AQT_O  0        // 4128 : Q rows 32x129 -> MSG rows
#define AKT_O  4128     // 4128 : K rows
#define AVT_O  8256     // 4128 : V rows
#define AST_O  12384    // 4096 : post-scan states
#define AST2_O 16480    // 4096 : states2 (cln output)
#define AAW_O  20576    // 4096 : attn weights [n][h*32+m]
#define ADIN_O 24672    // 256
#define AH1_O  24928    // 128
#define ADEC_O 25056    // 128
#define ANSV_O 25184    // 128
#define AINC_O 25312    // 128
#define ABCV_O 25440    // 128
#define APART_O 25568   // 1024
#define ARED_O 26592    // 128
#define SMEM_B 26720    // 106.9 KB

__global__ void __launch_bounds__(1024) k_attnbrains(int c,
        const float* __restrict__ st_in, const float* __restrict__ scanA,
        const float* __restrict__ Qg, const float* __restrict__ Kg, const float* __restrict__ Vg,
        const float* __restrict__ co_w, const float* __restrict__ co_b,
        const float* __restrict__ cln_g, const float* __restrict__ cln_b,
        const float* __restrict__ bcastv,
        const float* __restrict__ P_w, const float* __restrict__ P_b,
        const float* __restrict__ D1_w, const float* __restrict__ D1_b,
        const float* __restrict__ D2_w, const float* __restrict__ D2_b,
        const float* __restrict__ G_w, const float* __restrict__ G_b,
        const float* __restrict__ SM_w, const float* __restrict__ SM_b,
        const float* __restrict__ PR_w, const float* __restrict__ PR_b,
        const float* __restrict__ ln_g, const float* __restrict__ ln_b,
        float* __restrict__ st_out, float* __restrict__ prediction){
    int blk = blockIdx.x;
    // XCD swizzle: node n always lands on XCD n%8 -> each XCD L2 caches 4 nodes' weights
    int x8 = blk & 7, qq = blk >> 3;
    int n = x8 + 8*(qq & 3), b = qq >> 2;
    int tid = threadIdx.x, d2 = tid & 127, g = tid >> 7;
    __shared__ float smem[SMEM_B];
    float* part = &smem[APART_O];
    float* din  = &smem[ADIN_O];

    // stage Q/K/V/states
    for (int i=tid; i<N_*D_; i+=1024){
        int r = i>>7, dd = i&127;
        smem[AQT_O + r*129 + dd] = Qg[(b*N_+r)*D_+dd];
        smem[AKT_O + r*129 + dd] = Kg[(b*N_+r)*D_+dd];
        smem[AVT_O + r*129 + dd] = Vg[(b*N_+r)*D_+dd];
        smem[AST_O + i] = (r<S_)? scanA[b*S_*D_ + i] : st_in[(size_t)b*N_*D_ + i];
    }
    if (tid < D_) smem[ABCV_O+tid] = bcastv[b*D_+tid];
    __syncthreads();

    // scores + softmax for all 32 nodes (4 per thread)
    {
        const int h = d2>>5, m = d2&31;
        #pragma unroll
        for (int q=0;q<4;q++){
            int nn = q*8+g;
            float sdot = 0.f;
            #pragma unroll 8
            for (int j=0;j<HD_;j++) sdot += smem[AQT_O+nn*129+h*32+j]*smem[AKT_O+m*129+h*32+j];
            sdot *= 0.17677669529663687f; // 1/sqrt(32)
            float mx = sdot;
            #pragma unroll
            for (int off=16;off;off>>=1) mx = fmaxf(mx, __shfl_xor(mx, off, 32));
            float e = expf(sdot-mx);
            float Z = e;
            #pragma unroll
            for (int off=16;off;off>>=1) Z += __shfl_xor(Z, off, 32);
            smem[AAW_O+nn*128+h*32+m] = e/Z;
        }
    }
    __syncthreads();
    // msg rows overwrite Q rows (Q dead)
    {
        const int h = d2>>5;
        #pragma unroll
        for (int q=0;q<4;q++){
            int nn = q*8+g;
            float mm = 0.f;
            #pragma unroll 8
            for (int m2=0;m2<N_;m2++) mm += smem[AAW_O+nn*128+h*32+m2]*smem[AVT_O+m2*129+d2];
            smem[AQT_O+nn*129+d2] = mm;
        }
    }
    __syncthreads();
    // co + residual + cln-LN -> states2 for all 32 nodes
    {
        float acc2[4];
        #pragma unroll
        for (int q=0;q<4;q++) acc2[q] = co_b[d2];
        #pragma unroll 4
        for (int k=0;k<D_;k++){
            float w = co_w[k*D_+d2];
            #pragma unroll
            for (int q=0;q<4;q++) acc2[q] += smem[AQT_O+(q*8+g)*129+k]*w;
        }
        float xv[4];
        #pragma unroll
        for (int q=0;q<4;q++){
            xv[q] = smem[AST_O+(q*8+g)*D_+d2] + acc2[q];
            float s1 = xv[q], s2 = xv[q]*xv[q];
            #pragma unroll
            for (int off=32;off;off>>=1){ s1 += __shfl_xor(s1,off,64); s2 += __shfl_xor(s2,off,64); }
            if ((tid&63)==0){
                int base = ARED_O + (g*4+q)*4 + (d2>>6)*2;
                smem[base] = s1; smem[base+1] = s2;
            }
        }
        __syncthreads();
        #pragma unroll
        for (int q=0;q<4;q++){
            int base = ARED_O + (g*4+q)*4;
            float s1 = smem[base]+smem[base+2], s2 = smem[base+1]+smem[base+3];
            float mn  = s1*(1.0f/D_);
            float var = s2*(1.0f/D_) - mn*mn;
            smem[AST2_O+(q*8+g)*D_+d2] = (xv[q]-mn)*(1.0f/sqrtf(var+1e-5f))*cln_g[d2]+cln_b[d2];
        }
    }
    __syncthreads();
    // node-mean of states2 -> incoming
    if (tid < D_){
        float sm_ = 0.f;
        #pragma unroll 4
        for (int n2=0;n2<N_;n2++) sm_ += smem[AST2_O+n2*D_+tid];
        smem[AINC_O+tid] = sm_*(1.0f/N_);
    }
    __syncthreads();
    // prediction-error reduce (first 128 threads)
    const size_t rowb = ((size_t)b*N_+n)*D_;
    float* st2row = &smem[AST2_O + n*D_];
    float* incv   = &smem[AINC_O];
    float* bcv    = &smem[ABCV_O];
    if (g==0){
        float df = incv[d2] - prediction[rowb+d2];
        float s1 = df*df;
        #pragma unroll
        for (int off=32;off;off>>=1) s1 += __shfl_xor(s1, off, 64);
        if ((tid&63)==0) smem[ARED_O+(tid>>6)] = s1;
    }
    __syncthreads();
    float pe = (smem[ARED_O]+smem[ARED_O+1])*(1.0f/D_);
    float scale = (c>0)? (1.0f + 0.5f*sigm(pe*10.0f)) : 1.0f;
    // concurrent dots: P (K=384, g0..5; scale factored out of the inc block) | SM (K=128, g6..7)
    {
        float a = 0.f;
        if (g < 6){
            int src = g >> 1;                  // 0: incoming, 1: broadcast, 2: states2
            const float* xv = (src==0)? incv : (src==1)? bcv : st2row;
            int k0 = (g&1)*64;
            const float* Wn = P_w + ((size_t)n*384 + src*128 + k0)*D_ + d2;
            #pragma unroll 4
            for (int k=0;k<64;k++) a += xv[k0+k]*Wn[(size_t)k*D_];
        } else {
            int k0 = (g&1)*64;
            const float* Wn = SM_w + ((size_t)n*128 + k0)*D_ + d2;
            #pragma unroll 4
            for (int k=0;k<64;k++) a += st2row[k0+k]*Wn[(size_t)k*D_];
        }
        part[tid] = a;
    }
    __syncthreads();
    if (g==0){
        float v = scale*(part[d2]+part[128+d2]) + part[256+d2]+part[384+d2]+part[512+d2]+part[640+d2] + P_b[n*D_+d2];
        din[d2] = gelu_f(v);
    } else if (g==1){
        din[D_+d2] = part[768+d2]+part[896+d2] + SM_b[n*D_+d2];
    }
    __syncthreads();
    // D1: K=256 (8x32) -> h1 (gelu)
    {
        const float* Wn = D1_w + ((size_t)n*256 + g*32)*D_ + d2;
        float a=0;
        #pragma unroll 4
        for (int k=0;k<32;k++) a += din[g*32+k]*Wn[(size_t)k*D_];
        part[tid]=a;
    }
    __syncthreads();
    if (g==0){
        float v = part[d2]+part[128+d2]+part[256+d2]+part[384+d2]+part[512+d2]+part[640+d2]+part[768+d2]+part[896+d2] + D1_b[n*D_+d2];
        smem[AH1_O+d2] = gelu_f(v);
    }
    __syncthreads();
    // D2: K=128 (8x16) -> decision
    {
        const float* Wn = D2_w + ((size_t)n*128 + g*16)*D_ + d2;
        float a=0;
        #pragma unroll
        for (int k=0;k<16;k++) a += smem[AH1_O+g*16+k]*Wn[(size_t)k*D_];
        part[tid]=a;
    }
    __syncthreads();
    if (g==0){
        smem[ADEC_O+d2] = part[d2]+part[128+d2]+part[256+d2]+part[384+d2]+part[512+d2]+part[640+d2]+part[768+d2]+part[896+d2] + D2_b[n*D_+d2];
    }
    __syncthreads();
    // G: K=256: rows 0..127 = states2, rows 128..255 = decision
    {
        float a=0;
        if (g < 4){
            const float* Wn = G_w + ((size_t)n*256 + g*32)*D_ + d2;
            #pragma unroll 4
            for (int k=0;k<32;k++) a += st2row[g*32+k]*Wn[(size_t)k*D_];
        } else {
            const float* Wn = G_w + ((size_t)n*256 + 128 + (g-4)*32)*D_ + d2;
            #pragma unroll 4
            for (int k=0;k<32;k++) a += smem[ADEC_O+(g-4)*32+k]*Wn[(size_t)k*D_];
        }
        part[tid]=a;
    }
    __syncthreads();
    if (g==0){
        float gg = sigm(part[d2]+part[128+d2]+part[256+d2]+part[384+d2]+part[512+d2]+part[640+d2]+part[768+d2]+part[896+d2] + G_b[n*D_+d2]);
        float pre = gg*smem[ADEC_O+d2] + (1.0f-gg)*st2row[d2];
        smem[ANSV_O+d2] = pre;   // temp
        float s1 = pre, s2 = pre*pre;
        #pragma unroll
        for (int off=32;off;off>>=1){ s1 += __shfl_xor(s1, off, 64); s2 += __shfl_xor(s2, off, 64); }
        if ((tid&63)==0){ smem[ARED_O+(tid>>6)*2]=s1; smem[ARED_O+(tid>>6)*2+1]=s2; }
    }
    __syncthreads();
    if (g==0){
        float s1 = smem[ARED_O]+smem[ARED_O+2], s2 = smem[ARED_O+1]+smem[ARED_O+3];
        float mn = s1*(1.0f/D_);
        float var = s2*(1.0f/D_) - mn*mn;
        float pre = smem[ANSV_O+d2];
        float nv = (pre-mn)*(1.0f/sqrtf(var+1e-5f))*ln_g[d2]+ln_b[d2];
        smem[ANSV_O+d2]=nv;
        st_out[rowb+d2]=nv;
    }
    __syncthreads();
    // PR: K=128 (8x16) -> prediction
    {
        const float* Wn = PR_w + ((size_t)n*128 + g*16)*D_ + d2;
        float a=0;
        #pragma unroll
        for (int k=0;k<16;k++) a += smem[ANSV_O+g*16+k]*Wn[(size_t)k*D_];
        part[tid]=a;
    }
    __syncthreads();
    if (g==0){
        prediction[rowb+d2] = part[d2]+part[128+d2]+part[256+d2]+part[384+d2]+part[512+d2]+part[640+d2]+part[768+d2]+part[896+d2] + PR_b[n*D_+d2];
    }
}

// -------------------- f32 -> bf16 --------------------
__global__ void k_tobf16(const float* __restrict__ src, __hip_bfloat16* __restrict__ dst, int nelem){
    int i = blockIdx.x*256 + threadIdx.x;
    int stride = gridDim.x*256;
    for (; i<nelem; i+=stride) dst[i] = __float2bfloat16(src[i]);
}

// -------------------- final logits GEMM: (2048x128) @ (128x32000) + bias --------------------
typedef __attribute__((ext_vector_type(8))) short short8;
typedef __attribute__((ext_vector_type(4))) float f32x4;

__global__ void __launch_bounds__(256) k_gemm(const __hip_bfloat16* __restrict__ A,  // proj bf16, M x 128
                       const __hip_bfloat16* __restrict__ Bv,                        // emb bf16, V x 128
                       const float* __restrict__ out_bias,
                       float* __restrict__ out){
    int vblk = blockIdx.x;   // 125 blocks * 256 v
    int mblk = blockIdx.y;   // 32 blocks * 64 m
    int tid = threadIdx.x;
    int wave = tid >> 6, lane = tid & 63;
    int l16 = lane & 15, quad = lane >> 4;
    int mrow = mblk*64 + wave*16 + l16;
    f32x4 acc[16];
    #pragma unroll
    for (int j=0;j<16;j++){ f32x4 z = {0.f,0.f,0.f,0.f}; acc[j]=z; }
    short8 afr[4];
    const short* Ap = reinterpret_cast<const short*>(A);
    #pragma unroll
    for (int ks=0;ks<4;ks++)
        afr[ks] = *reinterpret_cast<const short8*>(Ap + mrow*128 + ks*32 + quad*8);
    const short* Bp = reinterpret_cast<const short*>(Bv);
    int vcolbase = vblk*256;
    #pragma unroll
    for (int jj=0;jj<16;jj++){
        int v = vcolbase + jj*16 + l16;
        #pragma unroll
        for (int ks=0;ks<4;ks++){
            short8 bfr = *reinterpret_cast<const short8*>(Bp + (size_t)v*128 + ks*32 + quad*8);
            acc[jj] = __builtin_amdgcn_mfma_f32_16x16x32_bf16(afr[ks], bfr, acc[jj], 0,0,0);
        }
    }
    int mbase = mblk*64 + wave*16 + quad*4;
    #pragma unroll
    for (int jj=0;jj<16;jj++){
        int v = vcolbase + jj*16 + l16;
        float bias = out_bias[v];
        #pragma unroll
        for (int r=0;r<4;r++){
            out[(size_t)(mbase+r)*V_ + v] = acc[jj][r] + bias;
        }
    }
}

extern "C" void kernel_launch(void* const* d_in, const int* in_sizes, int n_in,
                              void* d_out, int out_size, void* d_ws, size_t ws_size,
                              hipStream_t stream){
    (void)in_sizes; (void)n_in; (void)out_size; (void)ws_size;
    const int*   idx      = (const int*)  d_in[0];
    const float* emb      = (const float*)d_in[1];
    const float* pos_emb  = (const float*)d_in[2];
    const float* ifc_w    = (const float*)d_in[3];
    const float* ifc_b    = (const float*)d_in[4];
    const float* ifc_g    = (const float*)d_in[5];
    const float* ifc_beta = (const float*)d_in[6];
    const float* sproj_w  = (const float*)d_in[7];
    const float* sproj_b  = (const float*)d_in[8];
    const float* sgate_w  = (const float*)d_in[9];
    const float* sgate_b  = (const float*)d_in[10];
    const float* P_w  = (const float*)d_in[11];
    const float* P_b  = (const float*)d_in[12];
    const float* D1_w = (const float*)d_in[13];
    const float* D1_b = (const float*)d_in[14];
    const float* D2_w = (const float*)d_in[15];
    const float* D2_b = (const float*)d_in[16];
    // d_in[17], d_in[18]: A_w, A_b -- unused by the reference output
    const float* G_w  = (const float*)d_in[19];
    const float* G_b  = (const float*)d_in[20];
    const float* SM_w = (const float*)d_in[21];
    const float* SM_b = (const float*)d_in[22];
    const float* PR_w = (const float*)d_in[23];
    const float* PR_b = (const float*)d_in[24];
    const float* cq_w = (const float*)d_in[25];
    const float* cq_b = (const float*)d_in[26];
    const float* ck_w = (const float*)d_in[27];
    const float* ck_b = (const float*)d_in[28];
    const float* cv_w = (const float*)d_in[29];
    const float* cv_b = (const float*)d_in[30];
    const float* co_w = (const float*)d_in[31];
    const float* co_b = (const float*)d_in[32];
    const float* cln_g = (const float*)d_in[33];
    const float* cln_b = (const float*)d_in[34];
    const float* sal_w = (const float*)d_in[35];
    const float* sal_b = (const float*)d_in[36];
    const float* bcast_w = (const float*)d_in[37];
    const float* bcast_b = (const float*)d_in[38];
    const float* wln_g = (const float*)d_in[39];
    const float* wln_b = (const float*)d_in[40];
    const float* res_w = (const float*)d_in[41];
    const float* res_b = (const float*)d_in[42];
    const float* out_w = (const float*)d_in[43];
    const float* out_b = (const float*)d_in[44];
    const float* out_bias = (const float*)d_in[45];
    const float* ln_g = (const float*)d_in[46];
    const float* ln_b = (const float*)d_in[47];

    float* ws = (float*)d_ws;
    float* stE        = ws + 0;          // 32768
    float* prediction = ws + 32768;      // 32768
    float* stO        = ws + 65536;      // 32768
    float* scanA      = ws + 98304;      // 8192
    float* bcastv     = ws + 106496;     // 1024
    float* Qg         = ws + 107520;     // 32768
    float* Kg         = ws + 140288;     // 32768
    float* Vg         = ws + 173056;     // 32768
    float* percepts   = ws + 205824;     // 262144
    float* sensory    = ws + 467968;     // 2097152
    float* sg_sens    = ws + 2565120;    // 2097152
    float* outresb    = ws + 4662272;    // 262144
    float* projb      = ws + 4924416;    // 262144
    __hip_bfloat16* proj_bf = (__hip_bfloat16*)(ws + 5186560);  // 262144 bf16
    __hip_bfloat16* emb_bf  = (__hip_bfloat16*)(ws + 5317632);  // 4096000 bf16

    // zero the carried state (stE + prediction are contiguous)
    hipMemsetAsync(stE, 0, 2*32768*sizeof(float), stream);

    k_tobf16<<<512,256,0,stream>>>(emb, emb_bf, V_*D_);
    k_percepts<<<B_*T_,128,0,stream>>>(idx, emb, pos_emb, ifc_w, ifc_b, ifc_g, ifc_beta, percepts);
    k_precomp<<<256,256,0,stream>>>(percepts, sproj_w, sproj_b, sgate_w, res_w, res_b, out_w,
                                    sensory, sg_sens, outresb);
    for (int c=0;c<NCHUNK;c++){
        const float* stin = (c&1)? stO : stE;
        float* stout      = (c&1)? stE : stO;
        k_scan<<<B_,1024,0,stream>>>(c, sensory, sg_sens, sgate_w, sgate_b, sal_w, sal_b,
                                     out_w, out_b, outresb, bcast_w, bcast_b, wln_g, wln_b,
                                     cq_w,cq_b, ck_w,ck_b, cv_w,cv_b,
                                     stin, scanA, bcastv, Qg, Kg, Vg, projb);
        k_attnbrains<<<256,1024,0,stream>>>(c, stin, scanA, Qg, Kg, Vg, co_w, co_b,
                                            cln_g, cln_b, bcastv,
                                            P_w,P_b, D1_w,D1_b, D2_w,D2_b, G_w,G_b,
                                            SM_w,SM_b, PR_w,PR_b, ln_g,ln_b,
                                            stout, prediction);
    }
    k_tobf16<<<256,256,0,stream>>>(projb, proj_bf, B_*T_*D_);
    k_gemm<<<dim3(125,32),256,0,stream>>>(proj_bf, emb_bf, out_bias, (float*)d_out);
}